// Round 2
// baseline (1876.341 us; speedup 1.0000x reference)
//
#include <hip/hip_runtime.h>
#include <hip/hip_bf16.h>
#include <stdint.h>

typedef unsigned short u16;
typedef __attribute__((ext_vector_type(8))) short short8;
typedef __attribute__((ext_vector_type(4))) float f32x4;

#define LN_EPS 1e-5f
#define ATT_EPS 1e-8f

static __device__ __forceinline__ u16 f2bf(float f){
  uint32_t x = __float_as_uint(f);
  x += 0x7fffu + ((x >> 16) & 1u);
  return (u16)(x >> 16);
}
static __device__ __forceinline__ float bf2f(u16 u){
  return __uint_as_float(((uint32_t)u) << 16);
}
static __device__ __forceinline__ uint4 pack8(const u16* u){
  uint4 p;
  p.x = (uint32_t)u[0] | ((uint32_t)u[1] << 16);
  p.y = (uint32_t)u[2] | ((uint32_t)u[3] << 16);
  p.z = (uint32_t)u[4] | ((uint32_t)u[5] << 16);
  p.w = (uint32_t)u[6] | ((uint32_t)u[7] << 16);
  return p;
}

// ---------------- init slots: mu + exp(logsigma)*noise ----------------
__global__ __launch_bounds__(256) void init_slots_k(
    const float* __restrict__ noise, const float* __restrict__ mu,
    const float* __restrict__ lsig, float* __restrict__ slots)
{
  int i = blockIdx.x * 256 + threadIdx.x;   // 65536 total
  int d = i & 255;
  slots[i] = mu[d] + __expf(lsig[d]) * noise[i];
}

// ---------------- prep weights: WkT hi/lo bf16 split, wihT/whhT f32 ----------------
__global__ __launch_bounds__(256) void prep_w_k(
    const float* __restrict__ Wk, const float* __restrict__ wih,
    const float* __restrict__ whh,
    u16* __restrict__ WkT_hi, u16* __restrict__ WkT_lo,
    float* __restrict__ wihT, float* __restrict__ whhT)
{
  int i = blockIdx.x * 256 + threadIdx.x;   // grid 768 -> 196608
  if (i < 65536) {                           // WkT[c][kd] = Wk[kd][c]
    int c = i >> 8, kd = i & 255;
    float w = Wk[kd * 256 + c];
    u16 hi = f2bf(w);
    WkT_hi[i] = hi;
    WkT_lo[i] = f2bf(w - bf2f(hi));
  }
  // wihT[d][j] = wih[j][d]  (256 x 768)
  int d = i / 768, j = i - d * 768;
  wihT[i] = wih[j * 256 + d];
  whhT[i] = whh[j * 256 + d];
}

// ---------------- fused LN + x_ln @ Wk, split-bf16 MFMA, f32 out ----------------
// grid (2048, 4), block 256. Tile 64 rows x 64 cols, K chunked 128 x 2.
__global__ __launch_bounds__(256) void ln_k_gemm(
    const float* __restrict__ inputs, const float* __restrict__ g_in,
    const float* __restrict__ b_in, const u16* __restrict__ WkT_hi,
    const u16* __restrict__ WkT_lo, float* __restrict__ kbuf,
    float* __restrict__ lnm, float* __restrict__ lnr)
{
  __shared__ u16 AsH[64 * 128];   // 16KB each; total exactly 64KB
  __shared__ u16 AsL[64 * 128];
  __shared__ u16 BsH[64 * 128];
  __shared__ u16 BsL[64 * 128];

  int t = threadIdx.x;
  int r = t >> 2, seg = t & 3;
  long rowg = (long)blockIdx.x * 64 + r;
  const float4* src = (const float4*)(inputs + rowg * 256 + seg * 64);
  float vals[64];
  float s1 = 0.f, s2 = 0.f;
#pragma unroll
  for (int i = 0; i < 16; i++) {
    float4 v = src[i];
    vals[4 * i + 0] = v.x; vals[4 * i + 1] = v.y;
    vals[4 * i + 2] = v.z; vals[4 * i + 3] = v.w;
    s1 += v.x + v.y + v.z + v.w;
    s2 += v.x * v.x + v.y * v.y + v.z * v.z + v.w * v.w;
  }
  // reduce over the 4 lanes of this row (lanes 4r..4r+3, same wave)
  s1 += __shfl_xor(s1, 1); s1 += __shfl_xor(s1, 2);
  s2 += __shfl_xor(s2, 1); s2 += __shfl_xor(s2, 2);
  float m = s1 * (1.f / 256.f);
  float var = s2 * (1.f / 256.f) - m * m;
  float rs = rsqrtf(var + LN_EPS);
  if (blockIdx.y == 0 && seg == 0) { lnm[rowg] = m; lnr[rowg] = rs; }
#pragma unroll
  for (int j = 0; j < 64; j++) {
    int c = seg * 64 + j;
    vals[j] = (vals[j] - m) * rs * g_in[c] + b_in[c];
  }

  int w = t >> 6, l = t & 63;
  int lr = l & 15, lk = l >> 4;
  f32x4 acc[4] = {{0,0,0,0},{0,0,0,0},{0,0,0,0},{0,0,0,0}};

  for (int kc = 0; kc < 2; kc++) {
    // A staging: threads whose segs fall in this K-chunk
    if ((seg >> 1) == kc) {
      int half = seg & 1;
#pragma unroll
      for (int i = 0; i < 8; i++) {
        u16 hi8[8], lo8[8];
#pragma unroll
        for (int j = 0; j < 8; j++) {
          float v = vals[i * 8 + j];
          u16 h = f2bf(v);
          hi8[j] = h;
          lo8[j] = f2bf(v - bf2f(h));
        }
        int ad = r * 256 + half * 128 + i * 16;
        ad ^= (r & 7) << 4;
        *(uint4*)((char*)AsH + ad) = pack8(hi8);
        *(uint4*)((char*)AsL + ad) = pack8(lo8);
      }
    }
    // B staging: 64 cols x 128 k per chunk
    {
      int col = t >> 2, kq = t & 3;
      int colg = blockIdx.y * 64 + col;
      const uint4* gh = (const uint4*)(WkT_hi + colg * 256 + kc * 128 + kq * 32);
      const uint4* gl = (const uint4*)(WkT_lo + colg * 256 + kc * 128 + kq * 32);
#pragma unroll
      for (int jj = 0; jj < 4; jj++) {
        int ad = col * 256 + kq * 64 + jj * 16;
        ad ^= (col & 7) << 4;
        *(uint4*)((char*)BsH + ad) = gh[jj];
        *(uint4*)((char*)BsL + ad) = gl[jj];
      }
    }
    __syncthreads();
#pragma unroll
    for (int kk = 0; kk < 4; kk++) {
      int row = w * 16 + lr;
      int ka = kk * 64 + lk * 16;      // byte offset of k within chunk
      int adA = row * 256 + ka; adA ^= (row & 7) << 4;
      short8 ah = *(const short8*)((const char*)AsH + adA);
      short8 al = *(const short8*)((const char*)AsL + adA);
#pragma unroll
      for (int fc = 0; fc < 4; fc++) {
        int col = fc * 16 + lr;
        int adB = col * 256 + ka; adB ^= (col & 7) << 4;
        short8 bh = *(const short8*)((const char*)BsH + adB);
        short8 bl = *(const short8*)((const char*)BsL + adB);
        acc[fc] = __builtin_amdgcn_mfma_f32_16x16x32_bf16(ah, bh, acc[fc], 0, 0, 0);
        acc[fc] = __builtin_amdgcn_mfma_f32_16x16x32_bf16(ah, bl, acc[fc], 0, 0, 0);
        acc[fc] = __builtin_amdgcn_mfma_f32_16x16x32_bf16(al, bh, acc[fc], 0, 0, 0);
      }
    }
    __syncthreads();
  }
  // C/D layout: col = lane&15, row = (lane>>4)*4 + reg
  long rowbase = (long)blockIdx.x * 64 + w * 16 + (l >> 4) * 4;
  int colbase = blockIdx.y * 64;
#pragma unroll
  for (int fc = 0; fc < 4; fc++) {
#pragma unroll
    for (int reg = 0; reg < 4; reg++) {
      long row = rowbase + reg;
      int col = colbase + fc * 16 + lr;
      kbuf[row * 256 + col] = acc[fc][reg];
    }
  }
}

// ---------------- q = LN(slots) @ Wq ----------------
__global__ __launch_bounds__(256) void slot_q_k(
    const float* __restrict__ slots, const float* __restrict__ g_sl,
    const float* __restrict__ b_sl, const float* __restrict__ Wq,
    float* __restrict__ q)
{
  __shared__ float ln[256];
  __shared__ float red[8];
  int t = threadIdx.x;
  for (int rr = 0; rr < 4; rr++) {
    int i = blockIdx.x * 4 + rr;
    float x = slots[i * 256 + t];
    float a = x, bq = x * x;
#pragma unroll
    for (int off = 32; off; off >>= 1) { a += __shfl_down(a, off); bq += __shfl_down(bq, off); }
    if ((t & 63) == 0) { red[t >> 6] = a; red[4 + (t >> 6)] = bq; }
    __syncthreads();
    float S1 = red[0] + red[1] + red[2] + red[3];
    float S2 = red[4] + red[5] + red[6] + red[7];
    float m = S1 * (1.f / 256.f);
    float var = S2 * (1.f / 256.f) - m * m;
    float rstd = rsqrtf(var + LN_EPS);
    ln[t] = (x - m) * rstd * g_sl[t] + b_sl[t];
    __syncthreads();
    float acc = 0.f;
#pragma unroll 4
    for (int d = 0; d < 256; d++) acc += ln[d] * Wq[d * 256 + t];
    q[i * 256 + t] = acc;
    __syncthreads();
  }
}

__global__ __launch_bounds__(256) void zero_k(float* __restrict__ p, int n)
{
  int i = blockIdx.x * 256 + threadIdx.x;
  if (i < n) p[i] = 0.f;
}

// ---------------- fused dots + softmax(slots) + weighted-mean-of-x_ln ----------------
// grid (32 b, 16 nchunk), block 256. Per block: 256 n's.
// Phase A: thread (hs = t&31, nslot = t>>5) computes logits/softmax for its n's.
// Phase B: thread (d8 = t&31, hg = t>>5) accumulates y[hs][d] partials.
__global__ __launch_bounds__(256) void attn_fused_k(
    const float* __restrict__ kbuf, const float* __restrict__ qv,
    const float* __restrict__ inputs, const float* __restrict__ lnm,
    const float* __restrict__ lnr, const float* __restrict__ g_in,
    const float* __restrict__ b_in, float* __restrict__ y,
    float* __restrict__ sums)
{
  __shared__ float att[256][32];     // [n_local][hs]
  __shared__ float mrow[256], rrow[256];
  __shared__ float sred[4][32];
  int b = blockIdx.x, nb = blockIdx.y * 256, t = threadIdx.x;
  mrow[t] = lnm[b * 4096 + nb + t];
  rrow[t] = lnr[b * 4096 + nb + t];

  int hs = t & 31, nslot = t >> 5;
  int h = hs >> 3, s = hs & 7;
  float4 qr[16];
  const float4* qp = (const float4*)(qv + (b * 8 + s) * 256 + h * 64);
#pragma unroll
  for (int c = 0; c < 16; c++) qr[c] = qp[c];
  __syncthreads();

  float asum = 0.f;
  for (int jn = 0; jn < 32; jn++) {
    int nl = nslot * 32 + jn;
    const float4* kp = (const float4*)(kbuf + ((long)(b * 4096 + nb + nl)) * 256 + h * 64);
    float d = 0.f;
#pragma unroll
    for (int c = 0; c < 16; c++) {
      float4 k4 = kp[c];
      d += qr[c].x * k4.x + qr[c].y * k4.y + qr[c].z * k4.z + qr[c].w * k4.w;
    }
    d *= 0.125f;
    float mx = d;
    mx = fmaxf(mx, __shfl_xor(mx, 1));
    mx = fmaxf(mx, __shfl_xor(mx, 2));
    mx = fmaxf(mx, __shfl_xor(mx, 4));
    float e = __expf(d - mx);
    float se = e;
    se += __shfl_xor(se, 1); se += __shfl_xor(se, 2); se += __shfl_xor(se, 4);
    float a = e / se;
    asum += a;
    att[nl][hs] = a;
  }
  // reduce asum over nslots (bit5 within wave, then cross-wave via LDS)
  asum += __shfl_xor(asum, 32);
  int w = t >> 6, l = t & 63;
  if (l < 32) sred[w][l] = asum;
  __syncthreads();
  if (t < 32) {
    float v = sred[0][t] + sred[1][t] + sred[2][t] + sred[3][t];
    atomicAdd(&sums[b * 32 + t], v);
  }

  // Phase B
  int d8 = t & 31, hg = t >> 5;
  float gr[8], br[8];
#pragma unroll
  for (int j = 0; j < 8; j++) { gr[j] = g_in[d8 * 8 + j]; br[j] = b_in[d8 * 8 + j]; }
  float acc[32];
#pragma unroll
  for (int i = 0; i < 32; i++) acc[i] = 0.f;
  for (int nl = 0; nl < 256; nl++) {
    float m = mrow[nl], r = rrow[nl];
    const float4* xp = (const float4*)(inputs + ((long)(b * 4096 + nb + nl)) * 256 + d8 * 8);
    float4 x0 = xp[0], x1 = xp[1];
    float xv[8] = {x0.x, x0.y, x0.z, x0.w, x1.x, x1.y, x1.z, x1.w};
#pragma unroll
    for (int j = 0; j < 8; j++) xv[j] = (xv[j] - m) * r * gr[j] + br[j];
    float4 av = *(const float4*)&att[nl][hg * 4];
    float a4[4] = {av.x, av.y, av.z, av.w};
#pragma unroll
    for (int i = 0; i < 4; i++)
#pragma unroll
      for (int j = 0; j < 8; j++)
        acc[i * 8 + j] += a4[i] * xv[j];
  }
#pragma unroll
  for (int i = 0; i < 4; i++)
#pragma unroll
    for (int j = 0; j < 8; j++)
      atomicAdd(&y[((long)(b * 32 + hg * 4 + i)) * 256 + d8 * 8 + j], acc[i * 8 + j]);
}

// ---------------- combine: Wv-project + Wc + GRU + LN + MLP residual ----------------
// grid 128, block 256, 2 rows per block
__global__ __launch_bounds__(256) void combine_k(
    const float* __restrict__ y, const float* __restrict__ sums,
    float* __restrict__ slots, const float* __restrict__ Wv,
    const float* __restrict__ Wc, const float* __restrict__ wihT,
    const float* __restrict__ whhT, const float* __restrict__ bih,
    const float* __restrict__ bhh, const float* __restrict__ g_ml,
    const float* __restrict__ b_ml, const float* __restrict__ W1,
    const float* __restrict__ b1, const float* __restrict__ W2,
    const float* __restrict__ b2)
{
  __shared__ float ysn[4][256];
  __shared__ float uls[256], cls[256], hls[256], lns[256], hid[512];
  __shared__ float red[8];
  int t = threadIdx.x;
  for (int rr = 0; rr < 2; rr++) {
    int i = blockIdx.x * 2 + rr;
    int b = i >> 3, k = i & 7;
#pragma unroll
    for (int j = 0; j < 4; j++) {   // h = j
      float den = sums[b * 32 + j * 8 + k] + ATT_EPS;
      ysn[j][t] = y[((long)(b * 32 + j * 8 + k)) * 256 + t] / den;
    }
    hls[t] = slots[i * 256 + t];
    __syncthreads();
    {
      int h = t >> 6;
      float acc = 0.f;
#pragma unroll 4
      for (int d = 0; d < 256; d++) acc += ysn[h][d] * Wv[d * 256 + t];
      uls[t] = acc;
    }
    __syncthreads();
    float c = 0.f;
#pragma unroll 4
    for (int d = 0; d < 256; d++) c += uls[d] * Wc[d * 256 + t];
    cls[t] = c;
    __syncthreads();
    float gi0 = bih[t], gi1 = bih[256 + t], gi2 = bih[512 + t];
    float gh0 = bhh[t], gh1 = bhh[256 + t], gh2 = bhh[512 + t];
#pragma unroll 2
    for (int d = 0; d < 256; d++) {
      float u = cls[d], hh = hls[d];
      const float* wi = wihT + d * 768 + t;
      gi0 += u * wi[0]; gi1 += u * wi[256]; gi2 += u * wi[512];
      const float* wh = whhT + d * 768 + t;
      gh0 += hh * wh[0]; gh1 += hh * wh[256]; gh2 += hh * wh[512];
    }
    float r = 1.f / (1.f + __expf(-(gi0 + gh0)));
    float z = 1.f / (1.f + __expf(-(gi1 + gh1)));
    float nc = tanhf(gi2 + r * gh2);
    float sn = (1.f - z) * nc + z * hls[t];
    float a = sn, bq = sn * sn;
#pragma unroll
    for (int off = 32; off; off >>= 1) { a += __shfl_down(a, off); bq += __shfl_down(bq, off); }
    if ((t & 63) == 0) { red[t >> 6] = a; red[4 + (t >> 6)] = bq; }
    __syncthreads();
    float S1 = red[0] + red[1] + red[2] + red[3];
    float S2 = red[4] + red[5] + red[6] + red[7];
    float mean = S1 * (1.f / 256.f);
    float var = S2 * (1.f / 256.f) - mean * mean;
    float rstd = rsqrtf(var + LN_EPS);
    lns[t] = (sn - mean) * rstd * g_ml[t] + b_ml[t];
    __syncthreads();
    float h0 = b1[t], h1 = b1[256 + t];
#pragma unroll 2
    for (int d = 0; d < 256; d++) { float x = lns[d]; h0 += x * W1[d * 512 + t]; h1 += x * W1[d * 512 + 256 + t]; }
    hid[t] = fmaxf(h0, 0.f); hid[256 + t] = fmaxf(h1, 0.f);
    __syncthreads();
    float out = sn + b2[t];
#pragma unroll 2
    for (int hh = 0; hh < 512; hh++) out += hid[hh] * W2[hh * 256 + t];
    slots[i * 256 + t] = out;
    __syncthreads();
  }
}

extern "C" void kernel_launch(void* const* d_in, const int* in_sizes, int n_in,
                              void* d_out, int out_size, void* d_ws, size_t ws_size,
                              hipStream_t stream)
{
  const float* inputs = (const float*)d_in[0];
  const float* noise  = (const float*)d_in[1];
  const float* mu     = (const float*)d_in[2];
  const float* lsig   = (const float*)d_in[3];
  const float* g_in   = (const float*)d_in[4];
  const float* b_in   = (const float*)d_in[5];
  const float* g_sl   = (const float*)d_in[6];
  const float* b_sl   = (const float*)d_in[7];
  const float* g_ml   = (const float*)d_in[8];
  const float* b_ml   = (const float*)d_in[9];
  const float* Wq     = (const float*)d_in[10];
  const float* Wk     = (const float*)d_in[11];
  const float* Wv     = (const float*)d_in[12];
  const float* Wc     = (const float*)d_in[13];
  const float* wih    = (const float*)d_in[14];
  const float* whh    = (const float*)d_in[15];
  const float* bih    = (const float*)d_in[16];
  const float* bhh    = (const float*)d_in[17];
  const float* W1     = (const float*)d_in[18];
  const float* b1     = (const float*)d_in[19];
  const float* W2     = (const float*)d_in[20];
  const float* b2     = (const float*)d_in[21];

  char* ws = (char*)d_ws;
  float* kbuf   = (float*)(ws);                    // 134,217,728
  float* lnm    = (float*)(ws + 134217728);        //     524,288
  float* lnr    = (float*)(ws + 134742016);        //     524,288
  float* q      = (float*)(ws + 135266304);        //     262,144
  float* slots  = (float*)(ws + 135528448);        //     262,144
  float* y      = (float*)(ws + 135790592);        //   1,048,576
  float* sums   = (float*)(ws + 136839168);        //       4,096 (contig after y)
  u16*   WkT_hi = (u16*)(ws + 136843264);          //     131,072
  u16*   WkT_lo = (u16*)(ws + 136974336);          //     131,072
  float* wihT   = (float*)(ws + 137105408);        //     786,432
  float* whhT   = (float*)(ws + 137891840);        //     786,432

  init_slots_k<<<256, 256, 0, stream>>>(noise, mu, lsig, slots);
  prep_w_k<<<768, 256, 0, stream>>>(Wk, wih, whh, WkT_hi, WkT_lo, wihT, whhT);
  ln_k_gemm<<<dim3(2048, 4), 256, 0, stream>>>(inputs, g_in, b_in, WkT_hi, WkT_lo,
                                               kbuf, lnm, lnr);
  for (int it = 0; it < 3; ++it) {
    slot_q_k<<<64, 256, 0, stream>>>(slots, g_sl, b_sl, Wq, q);
    zero_k<<<1028, 256, 0, stream>>>(y, 263168);   // y + sums contiguous
    attn_fused_k<<<dim3(32, 16), 256, 0, stream>>>(kbuf, q, inputs, lnm, lnr,
                                                   g_in, b_in, y, sums);
    combine_k<<<128, 256, 0, stream>>>(y, sums, slots, Wv, Wc, wihT, whhT,
                                       bih, bhh, g_ml, b_ml, W1, b1, W2, b2);
  }
  hipMemcpyAsync(d_out, slots, 65536 * sizeof(float), hipMemcpyDeviceToDevice, stream);
}

// Round 3
// 1082.663 us; speedup vs baseline: 1.7331x; 1.7331x over previous
//
#include <hip/hip_runtime.h>
#include <hip/hip_bf16.h>
#include <stdint.h>

typedef unsigned short u16;
typedef __attribute__((ext_vector_type(8))) short short8;
typedef __attribute__((ext_vector_type(4))) float f32x4;

#define LN_EPS 1e-5f
#define ATT_EPS 1e-8f

static __device__ __forceinline__ u16 f2bf(float f){
  uint32_t x = __float_as_uint(f);
  x += 0x7fffu + ((x >> 16) & 1u);
  return (u16)(x >> 16);
}
static __device__ __forceinline__ float bf2f(u16 u){
  return __uint_as_float(((uint32_t)u) << 16);
}
static __device__ __forceinline__ uint4 pack8(const u16* u){
  uint4 p;
  p.x = (uint32_t)u[0] | ((uint32_t)u[1] << 16);
  p.y = (uint32_t)u[2] | ((uint32_t)u[3] << 16);
  p.z = (uint32_t)u[4] | ((uint32_t)u[5] << 16);
  p.w = (uint32_t)u[6] | ((uint32_t)u[7] << 16);
  return p;
}

// ---------------- init slots: mu + exp(logsigma)*noise ----------------
__global__ __launch_bounds__(256) void init_slots_k(
    const float* __restrict__ noise, const float* __restrict__ mu,
    const float* __restrict__ lsig, float* __restrict__ slots)
{
  int i = blockIdx.x * 256 + threadIdx.x;   // 65536 total
  int d = i & 255;
  slots[i] = mu[d] + __expf(lsig[d]) * noise[i];
}

// ---------------- prep weights: WkT hi/lo bf16 split, wihT/whhT f32 ----------------
__global__ __launch_bounds__(256) void prep_w_k(
    const float* __restrict__ Wk, const float* __restrict__ wih,
    const float* __restrict__ whh,
    u16* __restrict__ WkT_hi, u16* __restrict__ WkT_lo,
    float* __restrict__ wihT, float* __restrict__ whhT)
{
  int i = blockIdx.x * 256 + threadIdx.x;   // grid 768 -> 196608
  if (i < 65536) {                           // WkT[c][kd] = Wk[kd][c]
    int c = i >> 8, kd = i & 255;
    float w = Wk[kd * 256 + c];
    u16 hi = f2bf(w);
    WkT_hi[i] = hi;
    WkT_lo[i] = f2bf(w - bf2f(hi));
  }
  // wihT[d][j] = wih[j][d]  (256 x 768)
  int d = i / 768, j = i - d * 768;
  wihT[i] = wih[j * 256 + d];
  whhT[i] = whh[j * 256 + d];
}

// ---------------- fused LN + x_ln @ Wk, split-bf16 MFMA, f32 out ----------------
// grid (2048, 4), block 256. Tile 64 rows x 64 cols, K chunked 128 x 2.
__global__ __launch_bounds__(256) void ln_k_gemm(
    const float* __restrict__ inputs, const float* __restrict__ g_in,
    const float* __restrict__ b_in, const u16* __restrict__ WkT_hi,
    const u16* __restrict__ WkT_lo, float* __restrict__ kbuf,
    float* __restrict__ lnm, float* __restrict__ lnr)
{
  __shared__ u16 AsH[64 * 128];   // 16KB each; total exactly 64KB
  __shared__ u16 AsL[64 * 128];
  __shared__ u16 BsH[64 * 128];
  __shared__ u16 BsL[64 * 128];

  int t = threadIdx.x;
  int r = t >> 2, seg = t & 3;
  long rowg = (long)blockIdx.x * 64 + r;
  const float4* src = (const float4*)(inputs + rowg * 256 + seg * 64);
  float vals[64];
  float s1 = 0.f, s2 = 0.f;
#pragma unroll
  for (int i = 0; i < 16; i++) {
    float4 v = src[i];
    vals[4 * i + 0] = v.x; vals[4 * i + 1] = v.y;
    vals[4 * i + 2] = v.z; vals[4 * i + 3] = v.w;
    s1 += v.x + v.y + v.z + v.w;
    s2 += v.x * v.x + v.y * v.y + v.z * v.z + v.w * v.w;
  }
  // reduce over the 4 lanes of this row (lanes 4r..4r+3, same wave)
  s1 += __shfl_xor(s1, 1); s1 += __shfl_xor(s1, 2);
  s2 += __shfl_xor(s2, 1); s2 += __shfl_xor(s2, 2);
  float m = s1 * (1.f / 256.f);
  float var = s2 * (1.f / 256.f) - m * m;
  float rs = rsqrtf(var + LN_EPS);
  if (blockIdx.y == 0 && seg == 0) { lnm[rowg] = m; lnr[rowg] = rs; }
#pragma unroll
  for (int j = 0; j < 64; j++) {
    int c = seg * 64 + j;
    vals[j] = (vals[j] - m) * rs * g_in[c] + b_in[c];
  }

  int w = t >> 6, l = t & 63;
  int lr = l & 15, lk = l >> 4;
  f32x4 acc[4] = {{0,0,0,0},{0,0,0,0},{0,0,0,0},{0,0,0,0}};

  for (int kc = 0; kc < 2; kc++) {
    // A staging: threads whose segs fall in this K-chunk
    if ((seg >> 1) == kc) {
      int half = seg & 1;
#pragma unroll
      for (int i = 0; i < 8; i++) {
        u16 hi8[8], lo8[8];
#pragma unroll
        for (int j = 0; j < 8; j++) {
          float v = vals[i * 8 + j];
          u16 h = f2bf(v);
          hi8[j] = h;
          lo8[j] = f2bf(v - bf2f(h));
        }
        int ad = r * 256 + half * 128 + i * 16;
        ad ^= (r & 7) << 4;
        *(uint4*)((char*)AsH + ad) = pack8(hi8);
        *(uint4*)((char*)AsL + ad) = pack8(lo8);
      }
    }
    // B staging: 64 cols x 128 k per chunk
    {
      int col = t >> 2, kq = t & 3;
      int colg = blockIdx.y * 64 + col;
      const uint4* gh = (const uint4*)(WkT_hi + colg * 256 + kc * 128 + kq * 32);
      const uint4* gl = (const uint4*)(WkT_lo + colg * 256 + kc * 128 + kq * 32);
#pragma unroll
      for (int jj = 0; jj < 4; jj++) {
        int ad = col * 256 + kq * 64 + jj * 16;
        ad ^= (col & 7) << 4;
        *(uint4*)((char*)BsH + ad) = gh[jj];
        *(uint4*)((char*)BsL + ad) = gl[jj];
      }
    }
    __syncthreads();
#pragma unroll
    for (int kk = 0; kk < 4; kk++) {
      int row = w * 16 + lr;
      int ka = kk * 64 + lk * 16;      // byte offset of k within chunk
      int adA = row * 256 + ka; adA ^= (row & 7) << 4;
      short8 ah = *(const short8*)((const char*)AsH + adA);
      short8 al = *(const short8*)((const char*)AsL + adA);
#pragma unroll
      for (int fc = 0; fc < 4; fc++) {
        int col = fc * 16 + lr;
        int adB = col * 256 + ka; adB ^= (col & 7) << 4;
        short8 bh = *(const short8*)((const char*)BsH + adB);
        short8 bl = *(const short8*)((const char*)BsL + adB);
        acc[fc] = __builtin_amdgcn_mfma_f32_16x16x32_bf16(ah, bh, acc[fc], 0, 0, 0);
        acc[fc] = __builtin_amdgcn_mfma_f32_16x16x32_bf16(ah, bl, acc[fc], 0, 0, 0);
        acc[fc] = __builtin_amdgcn_mfma_f32_16x16x32_bf16(al, bh, acc[fc], 0, 0, 0);
      }
    }
    __syncthreads();
  }
  // C/D layout: col = lane&15, row = (lane>>4)*4 + reg
  long rowbase = (long)blockIdx.x * 64 + w * 16 + (l >> 4) * 4;
  int colbase = blockIdx.y * 64;
#pragma unroll
  for (int fc = 0; fc < 4; fc++) {
#pragma unroll
    for (int reg = 0; reg < 4; reg++) {
      long row = rowbase + reg;
      int col = colbase + fc * 16 + lr;
      kbuf[row * 256 + col] = acc[fc][reg];
    }
  }
}

// ---------------- q = LN(slots) @ Wq ----------------
// grid 256 (one slot row per block), block 1024 (k-split x4)
__global__ __launch_bounds__(1024) void slot_q_k(
    const float* __restrict__ slots, const float* __restrict__ g_sl,
    const float* __restrict__ b_sl, const float* __restrict__ Wq,
    float* __restrict__ q)
{
  __shared__ float ln[256];
  __shared__ float part[4][256];
  __shared__ float red[8];
  int t = threadIdx.x;
  int i = blockIdx.x;
  if (t < 256) {
    float x = slots[i * 256 + t];
    float a = x, bq = x * x;
#pragma unroll
    for (int off = 32; off; off >>= 1) { a += __shfl_down(a, off); bq += __shfl_down(bq, off); }
    if ((t & 63) == 0) { red[t >> 6] = a; red[4 + (t >> 6)] = bq; }
  }
  __syncthreads();
  if (t < 256) {
    float x = slots[i * 256 + t];
    float S1 = red[0] + red[1] + red[2] + red[3];
    float S2 = red[4] + red[5] + red[6] + red[7];
    float m = S1 * (1.f / 256.f);
    float var = S2 * (1.f / 256.f) - m * m;
    float rstd = rsqrtf(var + LN_EPS);
    ln[t] = (x - m) * rstd * g_sl[t] + b_sl[t];
  }
  __syncthreads();
  int col = t & 255, ks = t >> 8;
  float acc = 0.f;
#pragma unroll 16
  for (int dd = 0; dd < 64; dd++) {
    int d = ks * 64 + dd;
    acc += ln[d] * Wq[d * 256 + col];
  }
  part[ks][col] = acc;
  __syncthreads();
  if (t < 256) q[i * 256 + t] = part[0][t] + part[1][t] + part[2][t] + part[3][t];
}

__global__ __launch_bounds__(256) void zero_k(float* __restrict__ p, int n)
{
  int i = blockIdx.x * 256 + threadIdx.x;
  if (i < n) p[i] = 0.f;
}

// ---------------- fused dots + softmax(slots) + weighted-mean-of-x_ln ----------------
// grid (32 b, 16 nchunk), block 256. Per block: 256 n's.
__global__ __launch_bounds__(256) void attn_fused_k(
    const float* __restrict__ kbuf, const float* __restrict__ qv,
    const float* __restrict__ inputs, const float* __restrict__ lnm,
    const float* __restrict__ lnr, const float* __restrict__ g_in,
    const float* __restrict__ b_in, float* __restrict__ y,
    float* __restrict__ sums)
{
  __shared__ float att[256][32];     // [n_local][hs]
  __shared__ float mrow[256], rrow[256];
  __shared__ float sred[4][32];
  int b = blockIdx.x, nb = blockIdx.y * 256, t = threadIdx.x;
  mrow[t] = lnm[b * 4096 + nb + t];
  rrow[t] = lnr[b * 4096 + nb + t];

  int hs = t & 31, nslot = t >> 5;
  int h = hs >> 3, s = hs & 7;
  float4 qr[16];
  const float4* qp = (const float4*)(qv + (b * 8 + s) * 256 + h * 64);
#pragma unroll
  for (int c = 0; c < 16; c++) qr[c] = qp[c];
  __syncthreads();

  float asum = 0.f;
  for (int jn = 0; jn < 32; jn++) {
    int nl = nslot * 32 + jn;
    const float4* kp = (const float4*)(kbuf + ((long)(b * 4096 + nb + nl)) * 256 + h * 64);
    float d = 0.f;
#pragma unroll
    for (int c = 0; c < 16; c++) {
      float4 k4 = kp[c];
      d += qr[c].x * k4.x + qr[c].y * k4.y + qr[c].z * k4.z + qr[c].w * k4.w;
    }
    d *= 0.125f;
    float mx = d;
    mx = fmaxf(mx, __shfl_xor(mx, 1));
    mx = fmaxf(mx, __shfl_xor(mx, 2));
    mx = fmaxf(mx, __shfl_xor(mx, 4));
    float e = __expf(d - mx);
    float se = e;
    se += __shfl_xor(se, 1); se += __shfl_xor(se, 2); se += __shfl_xor(se, 4);
    float a = e / se;
    asum += a;
    att[nl][hs] = a;
  }
  // reduce asum over nslots (bit5 within wave, then cross-wave via LDS)
  asum += __shfl_xor(asum, 32);
  int w = t >> 6, l = t & 63;
  if (l < 32) sred[w][l] = asum;
  __syncthreads();
  if (t < 32) {
    float v = sred[0][t] + sred[1][t] + sred[2][t] + sred[3][t];
    atomicAdd(&sums[b * 32 + t], v);
  }

  // Phase B
  int d8 = t & 31, hg = t >> 5;
  float gr[8], br[8];
#pragma unroll
  for (int j = 0; j < 8; j++) { gr[j] = g_in[d8 * 8 + j]; br[j] = b_in[d8 * 8 + j]; }
  float acc[32];
#pragma unroll
  for (int i = 0; i < 32; i++) acc[i] = 0.f;
  for (int nl = 0; nl < 256; nl++) {
    float m = mrow[nl], r = rrow[nl];
    const float4* xp = (const float4*)(inputs + ((long)(b * 4096 + nb + nl)) * 256 + d8 * 8);
    float4 x0 = xp[0], x1 = xp[1];
    float xv[8] = {x0.x, x0.y, x0.z, x0.w, x1.x, x1.y, x1.z, x1.w};
#pragma unroll
    for (int j = 0; j < 8; j++) xv[j] = (xv[j] - m) * r * gr[j] + br[j];
    float4 av = *(const float4*)&att[nl][hg * 4];
    float a4[4] = {av.x, av.y, av.z, av.w};
#pragma unroll
    for (int i = 0; i < 4; i++)
#pragma unroll
      for (int j = 0; j < 8; j++)
        acc[i * 8 + j] += a4[i] * xv[j];
  }
#pragma unroll
  for (int i = 0; i < 4; i++)
#pragma unroll
    for (int j = 0; j < 8; j++)
      atomicAdd(&y[((long)(b * 32 + hg * 4 + i)) * 256 + d8 * 8 + j], acc[i * 8 + j]);
}

// ---------------- combine: Wv + Wc + GRU + LN + MLP residual ----------------
// grid 256 (one slot row per block), block 1024: all matvecs k-sliced + LDS reduce
__global__ __launch_bounds__(1024) void combine_k(
    const float* __restrict__ y, const float* __restrict__ sums,
    float* __restrict__ slots, const float* __restrict__ Wv,
    const float* __restrict__ Wc, const float* __restrict__ wihT,
    const float* __restrict__ whhT, const float* __restrict__ bih,
    const float* __restrict__ bhh, const float* __restrict__ g_ml,
    const float* __restrict__ b_ml, const float* __restrict__ W1,
    const float* __restrict__ b1, const float* __restrict__ W2,
    const float* __restrict__ b2)
{
  __shared__ float ysn[4][256];
  __shared__ float uls[256], cls[256], hls[256], sns[256], lns[256];
  __shared__ float gia[3][256], gha[3][256];
  __shared__ float hid[512];
  __shared__ float part2[4][256][2];
  __shared__ float part5[2][512];
  __shared__ float red[8];
  int t = threadIdx.x;
  int i = blockIdx.x;
  int b = i >> 3, k = i & 7;
  {
    int j = t >> 8, d = t & 255;
    float den = sums[b * 32 + j * 8 + k] + ATT_EPS;
    ysn[j][d] = y[((long)(b * 32 + j * 8 + k)) * 256 + d] / den;
    if (t < 256) hls[t] = slots[i * 256 + t];
  }
  __syncthreads();
  int col = t & 255, ks = t >> 8;
  // ---- Wv: uls = ysn[head(col)] @ Wv[:,col]
  {
    int h = col >> 6;
    float acc = 0.f;
#pragma unroll 16
    for (int dd = 0; dd < 64; dd++) {
      int d = ks * 64 + dd;
      acc += ysn[h][d] * Wv[d * 256 + col];
    }
    part2[ks][col][0] = acc;
  }
  __syncthreads();
  if (t < 256)
    uls[t] = part2[0][t][0] + part2[1][t][0] + part2[2][t][0] + part2[3][t][0];
  __syncthreads();
  // ---- Wc
  {
    float acc = 0.f;
#pragma unroll 16
    for (int dd = 0; dd < 64; dd++) {
      int d = ks * 64 + dd;
      acc += uls[d] * Wc[d * 256 + col];
    }
    part2[ks][col][0] = acc;
  }
  __syncthreads();
  if (t < 256)
    cls[t] = part2[0][t][0] + part2[1][t][0] + part2[2][t][0] + part2[3][t][0];
  __syncthreads();
  // ---- GRU gates (3 x two matvecs)
  for (int g = 0; g < 3; g++) {
    float ai = 0.f, ah = 0.f;
#pragma unroll 8
    for (int dd = 0; dd < 64; dd++) {
      int d = ks * 64 + dd;
      float wi = wihT[d * 768 + g * 256 + col];
      float wh = whhT[d * 768 + g * 256 + col];
      ai += cls[d] * wi;
      ah += hls[d] * wh;
    }
    part2[ks][col][0] = ai;
    part2[ks][col][1] = ah;
    __syncthreads();
    if (t < 256) {
      gia[g][t] = part2[0][t][0] + part2[1][t][0] + part2[2][t][0] + part2[3][t][0] + bih[g * 256 + t];
    } else if (t < 512) {
      int c = t & 255;
      gha[g][c] = part2[0][c][1] + part2[1][c][1] + part2[2][c][1] + part2[3][c][1] + bhh[g * 256 + c];
    }
    __syncthreads();
  }
  // ---- gates + LN (threads 0..255 = waves 0-3, full waves)
  if (t < 256) {
    float r = 1.f / (1.f + __expf(-(gia[0][t] + gha[0][t])));
    float z = 1.f / (1.f + __expf(-(gia[1][t] + gha[1][t])));
    float nc = tanhf(gia[2][t] + r * gha[2][t]);
    float sn = (1.f - z) * nc + z * hls[t];
    sns[t] = sn;
    float a = sn, bq = sn * sn;
#pragma unroll
    for (int off = 32; off; off >>= 1) { a += __shfl_down(a, off); bq += __shfl_down(bq, off); }
    if ((t & 63) == 0) { red[t >> 6] = a; red[4 + (t >> 6)] = bq; }
  }
  __syncthreads();
  if (t < 256) {
    float S1 = red[0] + red[1] + red[2] + red[3];
    float S2 = red[4] + red[5] + red[6] + red[7];
    float mean = S1 * (1.f / 256.f);
    float var = S2 * (1.f / 256.f) - mean * mean;
    float rstd = rsqrtf(var + LN_EPS);
    lns[t] = (sns[t] - mean) * rstd * g_ml[t] + b_ml[t];
  }
  __syncthreads();
  // ---- W1 (512 cols, k-split x2)
  {
    int c5 = t & 511, k5 = t >> 9;
    float acc = 0.f;
#pragma unroll 16
    for (int dd = 0; dd < 128; dd++) {
      int d = k5 * 128 + dd;
      acc += lns[d] * W1[d * 512 + c5];
    }
    part5[k5][c5] = acc;
  }
  __syncthreads();
  if (t < 512) hid[t] = fmaxf(part5[0][t] + part5[1][t] + b1[t], 0.f);
  __syncthreads();
  // ---- W2 (256 cols, k-split x4 over 512)
  {
    float acc = 0.f;
#pragma unroll 16
    for (int dd = 0; dd < 128; dd++) {
      int d = ks * 128 + dd;
      acc += hid[d] * W2[d * 256 + col];
    }
    part2[ks][col][0] = acc;
  }
  __syncthreads();
  if (t < 256)
    slots[i * 256 + t] = sns[t] + b2[t] +
        part2[0][t][0] + part2[1][t][0] + part2[2][t][0] + part2[3][t][0];
}

extern "C" void kernel_launch(void* const* d_in, const int* in_sizes, int n_in,
                              void* d_out, int out_size, void* d_ws, size_t ws_size,
                              hipStream_t stream)
{
  const float* inputs = (const float*)d_in[0];
  const float* noise  = (const float*)d_in[1];
  const float* mu     = (const float*)d_in[2];
  const float* lsig   = (const float*)d_in[3];
  const float* g_in   = (const float*)d_in[4];
  const float* b_in   = (const float*)d_in[5];
  const float* g_sl   = (const float*)d_in[6];
  const float* b_sl   = (const float*)d_in[7];
  const float* g_ml   = (const float*)d_in[8];
  const float* b_ml   = (const float*)d_in[9];
  const float* Wq     = (const float*)d_in[10];
  const float* Wk     = (const float*)d_in[11];
  const float* Wv     = (const float*)d_in[12];
  const float* Wc     = (const float*)d_in[13];
  const float* wih    = (const float*)d_in[14];
  const float* whh    = (const float*)d_in[15];
  const float* bih    = (const float*)d_in[16];
  const float* bhh    = (const float*)d_in[17];
  const float* W1     = (const float*)d_in[18];
  const float* b1     = (const float*)d_in[19];
  const float* W2     = (const float*)d_in[20];
  const float* b2     = (const float*)d_in[21];

  char* ws = (char*)d_ws;
  float* kbuf   = (float*)(ws);                    // 134,217,728
  float* lnm    = (float*)(ws + 134217728);        //     524,288
  float* lnr    = (float*)(ws + 134742016);        //     524,288
  float* q      = (float*)(ws + 135266304);        //     262,144
  float* slots  = (float*)(ws + 135528448);        //     262,144
  float* y      = (float*)(ws + 135790592);        //   1,048,576
  float* sums   = (float*)(ws + 136839168);        //       4,096 (contig after y)
  u16*   WkT_hi = (u16*)(ws + 136843264);          //     131,072
  u16*   WkT_lo = (u16*)(ws + 136974336);          //     131,072
  float* wihT   = (float*)(ws + 137105408);        //     786,432
  float* whhT   = (float*)(ws + 137891840);        //     786,432

  init_slots_k<<<256, 256, 0, stream>>>(noise, mu, lsig, slots);
  prep_w_k<<<768, 256, 0, stream>>>(Wk, wih, whh, WkT_hi, WkT_lo, wihT, whhT);
  ln_k_gemm<<<dim3(2048, 4), 256, 0, stream>>>(inputs, g_in, b_in, WkT_hi, WkT_lo,
                                               kbuf, lnm, lnr);
  for (int it = 0; it < 3; ++it) {
    slot_q_k<<<256, 1024, 0, stream>>>(slots, g_sl, b_sl, Wq, q);
    zero_k<<<1028, 256, 0, stream>>>(y, 263168);   // y + sums contiguous
    attn_fused_k<<<dim3(32, 16), 256, 0, stream>>>(kbuf, q, inputs, lnm, lnr,
                                                   g_in, b_in, y, sums);
    combine_k<<<256, 1024, 0, stream>>>(y, sums, slots, Wv, Wc, wihT, whhT,
                                        bih, bhh, g_ml, b_ml, W1, b1, W2, b2);
  }
  hipMemcpyAsync(d_out, slots, 65536 * sizeof(float), hipMemcpyDeviceToDevice, stream);
}

// Round 4
// 582.137 us; speedup vs baseline: 3.2232x; 1.8598x over previous
//
#include <hip/hip_runtime.h>
#include <hip/hip_bf16.h>
#include <stdint.h>

typedef unsigned short u16;
typedef _Float16 f16;
typedef __attribute__((ext_vector_type(8))) short short8;
typedef __attribute__((ext_vector_type(4))) float f32x4;
typedef __attribute__((ext_vector_type(8))) _Float16 h16x8;

#define LN_EPS 1e-5f
#define ATT_EPS 1e-8f

static __device__ __forceinline__ u16 f2bf(float f){
  uint32_t x = __float_as_uint(f);
  x += 0x7fffu + ((x >> 16) & 1u);
  return (u16)(x >> 16);
}
static __device__ __forceinline__ float bf2f(u16 u){
  return __uint_as_float(((uint32_t)u) << 16);
}
static __device__ __forceinline__ uint4 pack8(const u16* u){
  uint4 p;
  p.x = (uint32_t)u[0] | ((uint32_t)u[1] << 16);
  p.y = (uint32_t)u[2] | ((uint32_t)u[3] << 16);
  p.z = (uint32_t)u[4] | ((uint32_t)u[5] << 16);
  p.w = (uint32_t)u[6] | ((uint32_t)u[7] << 16);
  return p;
}

// ---------------- init slots: mu + exp(logsigma)*noise ----------------
__global__ __launch_bounds__(256) void init_slots_k(
    const float* __restrict__ noise, const float* __restrict__ mu,
    const float* __restrict__ lsig, float* __restrict__ slots)
{
  int i = blockIdx.x * 256 + threadIdx.x;   // 65536 total
  int d = i & 255;
  slots[i] = mu[d] + __expf(lsig[d]) * noise[i];
}

// ---------------- prep weights: WkT hi/lo bf16 split, wihT/whhT f32 ----------------
__global__ __launch_bounds__(256) void prep_w_k(
    const float* __restrict__ Wk, const float* __restrict__ wih,
    const float* __restrict__ whh,
    u16* __restrict__ WkT_hi, u16* __restrict__ WkT_lo,
    float* __restrict__ wihT, float* __restrict__ whhT)
{
  int i = blockIdx.x * 256 + threadIdx.x;   // grid 768 -> 196608
  if (i < 65536) {                           // WkT[c][kd] = Wk[kd][c]
    int c = i >> 8, kd = i & 255;
    float w = Wk[kd * 256 + c];
    u16 hi = f2bf(w);
    WkT_hi[i] = hi;
    WkT_lo[i] = f2bf(w - bf2f(hi));
  }
  // wihT[d][j] = wih[j][d]  (256 x 768)
  int d = i / 768, j = i - d * 768;
  wihT[i] = wih[j * 256 + d];
  whhT[i] = whh[j * 256 + d];
}

// ---------------- fused LN + x_ln @ Wk (split-bf16 MFMA), f16 k + f16 x_ln out ----
// grid 2048, block 512 (8 waves). Tile 64 rows x 256 cols, K chunked 64 x 4.
// LDS 80KB -> 2 blocks/CU (16 waves/CU).
__global__ __launch_bounds__(512, 4) void ln_k_gemm(
    const float* __restrict__ inputs, const float* __restrict__ g_in,
    const float* __restrict__ b_in, const u16* __restrict__ WkT_hi,
    const u16* __restrict__ WkT_lo, f16* __restrict__ kf16,
    f16* __restrict__ xln16)
{
  __shared__ u16 AsH[64 * 64];    // 8KB   [row][k64]
  __shared__ u16 AsL[64 * 64];    // 8KB
  __shared__ u16 BsH[256 * 64];   // 32KB  [col][k64]
  __shared__ u16 BsL[256 * 64];   // 32KB

  int t = threadIdx.x;
  int r = t >> 3, seg = t & 7;    // row 0..63, k-range [seg*32, +32)
  long rowg = (long)blockIdx.x * 64 + r;
  const float4* src = (const float4*)(inputs + rowg * 256 + seg * 32);
  float vals[32];
  float s1 = 0.f, s2 = 0.f;
#pragma unroll
  for (int i = 0; i < 8; i++) {
    float4 v = src[i];
    vals[4 * i + 0] = v.x; vals[4 * i + 1] = v.y;
    vals[4 * i + 2] = v.z; vals[4 * i + 3] = v.w;
    s1 += v.x + v.y + v.z + v.w;
    s2 += v.x * v.x + v.y * v.y + v.z * v.z + v.w * v.w;
  }
  // reduce over the 8 lanes covering this row (lane bits 0..2)
  s1 += __shfl_xor(s1, 1); s1 += __shfl_xor(s1, 2); s1 += __shfl_xor(s1, 4);
  s2 += __shfl_xor(s2, 1); s2 += __shfl_xor(s2, 2); s2 += __shfl_xor(s2, 4);
  float m = s1 * (1.f / 256.f);
  float var = s2 * (1.f / 256.f) - m * m;
  float rs = rsqrtf(var + LN_EPS);
#pragma unroll
  for (int j = 0; j < 32; j++) {
    int c = seg * 32 + j;
    vals[j] = (vals[j] - m) * rs * g_in[c] + b_in[c];
  }
  // store x_ln f16 (coalesced 64B/thread)
  {
    h16x8* xp = (h16x8*)(xln16 + rowg * 256 + seg * 32);
#pragma unroll
    for (int i2 = 0; i2 < 4; i2++) {
      h16x8 ov;
#pragma unroll
      for (int j = 0; j < 8; j++) ov[j] = (f16)vals[i2 * 8 + j];
      xp[i2] = ov;
    }
  }
  // precompute bf16 hi/lo packs (vals die here -> register relief)
  uint4 hiq[4], loq[4];
#pragma unroll
  for (int i2 = 0; i2 < 4; i2++) {
    u16 h8[8], l8[8];
#pragma unroll
    for (int j = 0; j < 8; j++) {
      float v = vals[i2 * 8 + j];
      u16 hh = f2bf(v);
      h8[j] = hh;
      l8[j] = f2bf(v - bf2f(hh));
    }
    hiq[i2] = pack8(h8); loq[i2] = pack8(l8);
  }

  int w = t >> 6, l = t & 63;
  int wr = (w & 3) * 16, wc = (w >> 2) * 128;
  int lr = l & 15, lk = l >> 4;
  f32x4 acc[8];
#pragma unroll
  for (int fc = 0; fc < 8; fc++) acc[fc] = (f32x4){0.f, 0.f, 0.f, 0.f};

  for (int kc = 0; kc < 4; kc++) {
    // stage A (threads owning this k-chunk: 2 of 8 segs)
    if ((seg >> 1) == kc) {
      int half = seg & 1;
#pragma unroll
      for (int i2 = 0; i2 < 4; i2++) {
        int ad = r * 128 + half * 64 + i2 * 16;
        ad ^= (r & 7) << 4;
        *(uint4*)((char*)AsH + ad) = hiq[i2];
        *(uint4*)((char*)AsL + ad) = loq[i2];
      }
    }
    // stage B: 256 cols x 64 k (hi+lo), 2 threads/col
    {
      int col = t >> 1, half = t & 1;
      const uint4* gh = (const uint4*)(WkT_hi + col * 256 + kc * 64 + half * 32);
      const uint4* gl = (const uint4*)(WkT_lo + col * 256 + kc * 64 + half * 32);
#pragma unroll
      for (int i2 = 0; i2 < 4; i2++) {
        int ad = col * 128 + half * 64 + i2 * 16;
        ad ^= (col & 7) << 4;
        *(uint4*)((char*)BsH + ad) = gh[i2];
        *(uint4*)((char*)BsL + ad) = gl[i2];
      }
    }
    __syncthreads();
#pragma unroll
    for (int kk = 0; kk < 2; kk++) {
      int row = wr + lr;
      int adA = row * 128 + kk * 64 + lk * 16; adA ^= (row & 7) << 4;
      short8 ah = *(const short8*)((const char*)AsH + adA);
      short8 al = *(const short8*)((const char*)AsL + adA);
#pragma unroll
      for (int fc = 0; fc < 8; fc++) {
        int col = wc + fc * 16 + lr;
        int adB = col * 128 + kk * 64 + lk * 16; adB ^= (col & 7) << 4;
        short8 bh = *(const short8*)((const char*)BsH + adB);
        short8 bl = *(const short8*)((const char*)BsL + adB);
        acc[fc] = __builtin_amdgcn_mfma_f32_16x16x32_bf16(ah, bh, acc[fc], 0, 0, 0);
        acc[fc] = __builtin_amdgcn_mfma_f32_16x16x32_bf16(ah, bl, acc[fc], 0, 0, 0);
        acc[fc] = __builtin_amdgcn_mfma_f32_16x16x32_bf16(al, bh, acc[fc], 0, 0, 0);
      }
    }
    __syncthreads();
  }
  // C/D layout: col = lane&15, row = (lane>>4)*4 + reg
  long rowbase = (long)blockIdx.x * 64 + wr + (l >> 4) * 4;
#pragma unroll
  for (int fc = 0; fc < 8; fc++) {
#pragma unroll
    for (int reg = 0; reg < 4; reg++) {
      kf16[(rowbase + reg) * 256 + wc + fc * 16 + lr] = (f16)acc[fc][reg];
    }
  }
}

// ---------------- q = LN(slots) @ Wq (iter 0 only) ----------------
// grid 256 (one slot row per block), block 1024 (k-split x4)
__global__ __launch_bounds__(1024) void slot_q_k(
    const float* __restrict__ slots, const float* __restrict__ g_sl,
    const float* __restrict__ b_sl, const float* __restrict__ Wq,
    float* __restrict__ q)
{
  __shared__ float ln[256];
  __shared__ float part[4][256];
  __shared__ float red[8];
  int t = threadIdx.x;
  int i = blockIdx.x;
  if (t < 256) {
    float x = slots[i * 256 + t];
    float a = x, bq = x * x;
#pragma unroll
    for (int off = 32; off; off >>= 1) { a += __shfl_down(a, off); bq += __shfl_down(bq, off); }
    if ((t & 63) == 0) { red[t >> 6] = a; red[4 + (t >> 6)] = bq; }
  }
  __syncthreads();
  if (t < 256) {
    float x = slots[i * 256 + t];
    float S1 = red[0] + red[1] + red[2] + red[3];
    float S2 = red[4] + red[5] + red[6] + red[7];
    float m = S1 * (1.f / 256.f);
    float var = S2 * (1.f / 256.f) - m * m;
    float rstd = rsqrtf(var + LN_EPS);
    ln[t] = (x - m) * rstd * g_sl[t] + b_sl[t];
  }
  __syncthreads();
  int col = t & 255, ks = t >> 8;
  float acc = 0.f;
#pragma unroll 16
  for (int dd = 0; dd < 64; dd++) {
    int d = ks * 64 + dd;
    acc += ln[d] * Wq[d * 256 + col];
  }
  part[ks][col] = acc;
  __syncthreads();
  if (t < 256) q[i * 256 + t] = part[0][t] + part[1][t] + part[2][t] + part[3][t];
}

// ---------------- fused dots + softmax(slots) + weighted-mean-of-x_ln ----------------
// grid (32 b, 16 nchunk), block 256. No atomics: per-chunk partials.
__global__ __launch_bounds__(256, 4) void attn_fused_k(
    const f16* __restrict__ kf16, const float* __restrict__ qv,
    const f16* __restrict__ xln16, f16* __restrict__ y_part,
    float* __restrict__ sums_part)
{
  __shared__ float att[256][32];     // [n_local][hs]  32KB
  __shared__ float sred[4][32];
  int b = blockIdx.x, nc = blockIdx.y, nb = nc * 256, t = threadIdx.x;

  int hs = t & 31, nslot = t >> 5;
  int h = hs >> 3, s = hs & 7;
  float qf[64];
  {
    const float4* qp = (const float4*)(qv + (b * 8 + s) * 256 + h * 64);
#pragma unroll
    for (int c = 0; c < 16; c++) {
      float4 v = qp[c];
      qf[4 * c + 0] = v.x; qf[4 * c + 1] = v.y;
      qf[4 * c + 2] = v.z; qf[4 * c + 3] = v.w;
    }
  }
  float asum = 0.f;
  for (int jn = 0; jn < 32; jn++) {
    int nl = nslot * 32 + jn;
    const h16x8* kp = (const h16x8*)(kf16 + ((long)(b * 4096 + nb + nl)) * 256 + h * 64);
    float d = 0.f;
#pragma unroll
    for (int c8 = 0; c8 < 8; c8++) {
      h16x8 kv = kp[c8];
#pragma unroll
      for (int j = 0; j < 8; j++) d += qf[c8 * 8 + j] * (float)kv[j];
    }
    d *= 0.125f;
    float mx = d;
    mx = fmaxf(mx, __shfl_xor(mx, 1));
    mx = fmaxf(mx, __shfl_xor(mx, 2));
    mx = fmaxf(mx, __shfl_xor(mx, 4));
    float e = __expf(d - mx);
    float se = e;
    se += __shfl_xor(se, 1); se += __shfl_xor(se, 2); se += __shfl_xor(se, 4);
    float a = e / se;
    asum += a;
    att[nl][hs] = a;
  }
  // reduce asum over nslots
  asum += __shfl_xor(asum, 32);
  int w = t >> 6, l = t & 63;
  if (l < 32) sred[w][l] = asum;
  __syncthreads();
  if (t < 32)
    sums_part[(nc * 32 + b) * 32 + t] = sred[0][t] + sred[1][t] + sred[2][t] + sred[3][t];

  // Phase B: y_part[nc][b][hs][d] accumulation
  int d8 = t & 31, hg = t >> 5;
  float acc[32];
#pragma unroll
  for (int i = 0; i < 32; i++) acc[i] = 0.f;
  for (int nl = 0; nl < 256; nl++) {
    h16x8 xv8 = *(const h16x8*)(xln16 + ((long)(b * 4096 + nb + nl)) * 256 + d8 * 8);
    float xv[8];
#pragma unroll
    for (int j = 0; j < 8; j++) xv[j] = (float)xv8[j];
    float4 av = *(const float4*)&att[nl][hg * 4];
    float a4[4] = {av.x, av.y, av.z, av.w};
#pragma unroll
    for (int i = 0; i < 4; i++)
#pragma unroll
      for (int j = 0; j < 8; j++)
        acc[i * 8 + j] += a4[i] * xv[j];
  }
#pragma unroll
  for (int i = 0; i < 4; i++) {
    h16x8 ov;
#pragma unroll
    for (int j = 0; j < 8; j++) ov[j] = (f16)acc[i * 8 + j];
    *(h16x8*)(y_part + ((long)((nc * 32 + b) * 32 + hg * 4 + i)) * 256 + d8 * 8) = ov;
  }
}

// ---------------- combine: y-reduce + Wv + Wc + GRU + LN + MLP (+ fused next-q) ----
// grid 256 (one slot row per block), block 1024
__global__ __launch_bounds__(1024) void combine_k(
    const f16* __restrict__ y_part, const float* __restrict__ sums_part,
    float* __restrict__ slots, const float* __restrict__ Wv,
    const float* __restrict__ Wc, const float* __restrict__ wihT,
    const float* __restrict__ whhT, const float* __restrict__ bih,
    const float* __restrict__ bhh, const float* __restrict__ g_ml,
    const float* __restrict__ b_ml, const float* __restrict__ W1,
    const float* __restrict__ b1, const float* __restrict__ W2,
    const float* __restrict__ b2, const float* __restrict__ g_sl,
    const float* __restrict__ b_sl, const float* __restrict__ Wq,
    float* __restrict__ q, int cq)
{
  __shared__ float ysn[4][256];
  __shared__ float uls[256], cls[256], hls[256], sns[256], lns[256];
  __shared__ float gia[3][256], gha[3][256];
  __shared__ float hid[512];
  __shared__ float part2[4][256][2];
  __shared__ float part5[2][512];
  __shared__ float red[8];
  int t = threadIdx.x;
  int i = blockIdx.x;
  int b = i >> 3, k = i & 7;
  {
    int j = t >> 8, d = t & 255;   // j = head
    float den = ATT_EPS, yv = 0.f;
#pragma unroll
    for (int ncq = 0; ncq < 16; ncq++) {
      int hsrow = (ncq * 32 + b) * 32 + j * 8 + k;
      den += sums_part[hsrow];
      yv += (float)y_part[(long)hsrow * 256 + d];
    }
    ysn[j][d] = yv / den;
    if (t < 256) hls[t] = slots[i * 256 + t];
  }
  __syncthreads();
  int col = t & 255, ks = t >> 8;
  // ---- Wv: uls = ysn[head(col)] @ Wv[:,col]
  {
    int h = col >> 6;
    float acc = 0.f;
#pragma unroll 16
    for (int dd = 0; dd < 64; dd++) {
      int d = ks * 64 + dd;
      acc += ysn[h][d] * Wv[d * 256 + col];
    }
    part2[ks][col][0] = acc;
  }
  __syncthreads();
  if (t < 256)
    uls[t] = part2[0][t][0] + part2[1][t][0] + part2[2][t][0] + part2[3][t][0];
  __syncthreads();
  // ---- Wc
  {
    float acc = 0.f;
#pragma unroll 16
    for (int dd = 0; dd < 64; dd++) {
      int d = ks * 64 + dd;
      acc += uls[d] * Wc[d * 256 + col];
    }
    part2[ks][col][0] = acc;
  }
  __syncthreads();
  if (t < 256)
    cls[t] = part2[0][t][0] + part2[1][t][0] + part2[2][t][0] + part2[3][t][0];
  __syncthreads();
  // ---- GRU gates
  for (int g = 0; g < 3; g++) {
    float ai = 0.f, ah = 0.f;
#pragma unroll 8
    for (int dd = 0; dd < 64; dd++) {
      int d = ks * 64 + dd;
      float wi = wihT[d * 768 + g * 256 + col];
      float wh = whhT[d * 768 + g * 256 + col];
      ai += cls[d] * wi;
      ah += hls[d] * wh;
    }
    part2[ks][col][0] = ai;
    part2[ks][col][1] = ah;
    __syncthreads();
    if (t < 256) {
      gia[g][t] = part2[0][t][0] + part2[1][t][0] + part2[2][t][0] + part2[3][t][0] + bih[g * 256 + t];
    } else if (t < 512) {
      int c = t & 255;
      gha[g][c] = part2[0][c][1] + part2[1][c][1] + part2[2][c][1] + part2[3][c][1] + bhh[g * 256 + c];
    }
    __syncthreads();
  }
  // ---- gates + LN
  if (t < 256) {
    float r = 1.f / (1.f + __expf(-(gia[0][t] + gha[0][t])));
    float z = 1.f / (1.f + __expf(-(gia[1][t] + gha[1][t])));
    float nc2 = tanhf(gia[2][t] + r * gha[2][t]);
    float sn = (1.f - z) * nc2 + z * hls[t];
    sns[t] = sn;
    float a = sn, bq = sn * sn;
#pragma unroll
    for (int off = 32; off; off >>= 1) { a += __shfl_down(a, off); bq += __shfl_down(bq, off); }
    if ((t & 63) == 0) { red[t >> 6] = a; red[4 + (t >> 6)] = bq; }
  }
  __syncthreads();
  if (t < 256) {
    float S1 = red[0] + red[1] + red[2] + red[3];
    float S2 = red[4] + red[5] + red[6] + red[7];
    float mean = S1 * (1.f / 256.f);
    float var = S2 * (1.f / 256.f) - mean * mean;
    float rstd = rsqrtf(var + LN_EPS);
    lns[t] = (sns[t] - mean) * rstd * g_ml[t] + b_ml[t];
  }
  __syncthreads();
  // ---- W1
  {
    int c5 = t & 511, k5 = t >> 9;
    float acc = 0.f;
#pragma unroll 16
    for (int dd = 0; dd < 128; dd++) {
      int d = k5 * 128 + dd;
      acc += lns[d] * W1[d * 512 + c5];
    }
    part5[k5][c5] = acc;
  }
  __syncthreads();
  if (t < 512) hid[t] = fmaxf(part5[0][t] + part5[1][t] + b1[t], 0.f);
  __syncthreads();
  // ---- W2
  {
    float acc = 0.f;
#pragma unroll 16
    for (int dd = 0; dd < 128; dd++) {
      int d = ks * 128 + dd;
      acc += hid[d] * W2[d * 256 + col];
    }
    part2[ks][col][0] = acc;
  }
  __syncthreads();
  float outv = 0.f;
  if (t < 256) {
    outv = sns[t] + b2[t] +
        part2[0][t][0] + part2[1][t][0] + part2[2][t][0] + part2[3][t][0];
    slots[i * 256 + t] = outv;
  }
  // ---- fused q for next iteration
  if (cq) {
    if (t < 256) {
      float a = outv, bq = outv * outv;
#pragma unroll
      for (int off = 32; off; off >>= 1) { a += __shfl_down(a, off); bq += __shfl_down(bq, off); }
      if ((t & 63) == 0) { red[t >> 6] = a; red[4 + (t >> 6)] = bq; }
    }
    __syncthreads();
    if (t < 256) {
      float S1 = red[0] + red[1] + red[2] + red[3];
      float S2 = red[4] + red[5] + red[6] + red[7];
      float mean = S1 * (1.f / 256.f);
      float var = S2 * (1.f / 256.f) - mean * mean;
      float rstd = rsqrtf(var + LN_EPS);
      lns[t] = (outv - mean) * rstd * g_sl[t] + b_sl[t];
    }
    __syncthreads();
    float accq = 0.f;
#pragma unroll 16
    for (int dd = 0; dd < 64; dd++) {
      int d = ks * 64 + dd;
      accq += lns[d] * Wq[d * 256 + col];
    }
    part2[ks][col][0] = accq;
    __syncthreads();
    if (t < 256)
      q[i * 256 + t] = part2[0][t][0] + part2[1][t][0] + part2[2][t][0] + part2[3][t][0];
  }
}

extern "C" void kernel_launch(void* const* d_in, const int* in_sizes, int n_in,
                              void* d_out, int out_size, void* d_ws, size_t ws_size,
                              hipStream_t stream)
{
  const float* inputs = (const float*)d_in[0];
  const float* noise  = (const float*)d_in[1];
  const float* mu     = (const float*)d_in[2];
  const float* lsig   = (const float*)d_in[3];
  const float* g_in   = (const float*)d_in[4];
  const float* b_in   = (const float*)d_in[5];
  const float* g_sl   = (const float*)d_in[6];
  const float* b_sl   = (const float*)d_in[7];
  const float* g_ml   = (const float*)d_in[8];
  const float* b_ml   = (const float*)d_in[9];
  const float* Wq     = (const float*)d_in[10];
  const float* Wk     = (const float*)d_in[11];
  const float* Wv     = (const float*)d_in[12];
  const float* Wc     = (const float*)d_in[13];
  const float* wih    = (const float*)d_in[14];
  const float* whh    = (const float*)d_in[15];
  const float* bih    = (const float*)d_in[16];
  const float* bhh    = (const float*)d_in[17];
  const float* W1     = (const float*)d_in[18];
  const float* b1     = (const float*)d_in[19];
  const float* W2     = (const float*)d_in[20];
  const float* b2     = (const float*)d_in[21];

  char* ws = (char*)d_ws;
  f16*   kf16   = (f16*)(ws);                      //  67,108,864
  f16*   xln16  = (f16*)(ws + 67108864);           //  67,108,864
  f16*   y_part = (f16*)(ws + 134217728);          //   8,388,608
  float* q      = (float*)(ws + 142606336);        //     262,144
  float* slots  = (float*)(ws + 142868480);        //     262,144
  float* sumsp  = (float*)(ws + 143130624);        //      65,536
  u16*   WkT_hi = (u16*)(ws + 143196160);          //     131,072
  u16*   WkT_lo = (u16*)(ws + 143327232);          //     131,072
  float* wihT   = (float*)(ws + 143458304);        //     786,432
  float* whhT   = (float*)(ws + 144244736);        //     786,432  -> end 145,031,168

  init_slots_k<<<256, 256, 0, stream>>>(noise, mu, lsig, slots);
  prep_w_k<<<768, 256, 0, stream>>>(Wk, wih, whh, WkT_hi, WkT_lo, wihT, whhT);
  ln_k_gemm<<<2048, 512, 0, stream>>>(inputs, g_in, b_in, WkT_hi, WkT_lo,
                                      kf16, xln16);
  slot_q_k<<<256, 1024, 0, stream>>>(slots, g_sl, b_sl, Wq, q);
  for (int it = 0; it < 3; ++it) {
    attn_fused_k<<<dim3(32, 16), 256, 0, stream>>>(kf16, q, xln16, y_part, sumsp);
    combine_k<<<256, 1024, 0, stream>>>(y_part, sumsp, slots, Wv, Wc, wihT, whhT,
                                        bih, bhh, g_ml, b_ml, W1, b1, W2, b2,
                                        g_sl, b_sl, Wq, q, (it < 2) ? 1 : 0);
  }
  hipMemcpyAsync(d_out, slots, 65536 * sizeof(float), hipMemcpyDeviceToDevice, stream);
}

// Round 5
// 396.315 us; speedup vs baseline: 4.7345x; 1.4689x over previous
//
#include <hip/hip_runtime.h>
#include <hip/hip_bf16.h>
#include <stdint.h>

typedef unsigned short u16;
typedef _Float16 f16;
typedef __attribute__((ext_vector_type(4))) float f32x4;
typedef __attribute__((ext_vector_type(8))) _Float16 h16x8;

#define LN_EPS 1e-5f
#define ATT_EPS 1e-8f

// ---------------- init slots: mu + exp(logsigma)*noise ----------------
__global__ __launch_bounds__(256) void init_slots_k(
    const float* __restrict__ noise, const float* __restrict__ mu,
    const float* __restrict__ lsig, float* __restrict__ slots)
{
  int i = blockIdx.x * 256 + threadIdx.x;   // 65536 total
  int d = i & 255;
  slots[i] = mu[d] + __expf(lsig[d]) * noise[i];
}

// ---------------- prep weights: WkT f16, wihT/whhT f32 ----------------
__global__ __launch_bounds__(256) void prep_w_k(
    const float* __restrict__ Wk, const float* __restrict__ wih,
    const float* __restrict__ whh,
    f16* __restrict__ WkT16, float* __restrict__ wihT, float* __restrict__ whhT)
{
  int i = blockIdx.x * 256 + threadIdx.x;   // grid 768 -> 196608
  if (i < 65536) {                           // WkT[c][kd] = Wk[kd][c]
    int c = i >> 8, kd = i & 255;
    WkT16[i] = (f16)Wk[kd * 256 + c];
  }
  int d = i / 768, j = i - d * 768;
  wihT[i] = wih[j * 256 + d];
  whhT[i] = whh[j * 256 + d];
}

// ---------------- pure LN pass: xln16 = LN(inputs) as f16 ----------------
// grid 2048, block 256: 64 rows/block, 4 threads/row
__global__ __launch_bounds__(256) void ln_x_k(
    const float* __restrict__ inputs, const float* __restrict__ g_in,
    const float* __restrict__ b_in, f16* __restrict__ xln16)
{
  int t = threadIdx.x;
  int r = t >> 2, seg = t & 3;
  long rowg = (long)blockIdx.x * 64 + r;
  const float4* src = (const float4*)(inputs + rowg * 256 + seg * 64);
  float vals[64];
  float s1 = 0.f, s2 = 0.f;
#pragma unroll
  for (int i = 0; i < 16; i++) {
    float4 v = src[i];
    vals[4 * i + 0] = v.x; vals[4 * i + 1] = v.y;
    vals[4 * i + 2] = v.z; vals[4 * i + 3] = v.w;
    s1 += v.x + v.y + v.z + v.w;
    s2 += v.x * v.x + v.y * v.y + v.z * v.z + v.w * v.w;
  }
  s1 += __shfl_xor(s1, 1); s1 += __shfl_xor(s1, 2);
  s2 += __shfl_xor(s2, 1); s2 += __shfl_xor(s2, 2);
  float m = s1 * (1.f / 256.f);
  float var = s2 * (1.f / 256.f) - m * m;
  float rs = rsqrtf(var + LN_EPS);
  h16x8* xp = (h16x8*)(xln16 + rowg * 256 + seg * 64);
#pragma unroll
  for (int i2 = 0; i2 < 8; i2++) {
    h16x8 ov;
#pragma unroll
    for (int j = 0; j < 8; j++) {
      int c = seg * 64 + i2 * 8 + j;
      ov[j] = (f16)((vals[i2 * 8 + j] - m) * rs * g_in[c] + b_in[c]);
    }
    xp[i2] = ov;
  }
}

// ---------------- t = (LN(slots)@Wq) projected through Wk heads, x SCALE ----
// grid 256 (one slot row per block), block 1024
__global__ __launch_bounds__(1024) void slot_t_k(
    const float* __restrict__ slots, const float* __restrict__ g_sl,
    const float* __restrict__ b_sl, const float* __restrict__ Wq,
    const f16* __restrict__ WkT16, f16* __restrict__ tq)
{
  __shared__ float ln[256];
  __shared__ float qs[256];
  __shared__ float part[4][256];
  __shared__ float red[8];
  int t = threadIdx.x;
  int i = blockIdx.x;
  if (t < 256) {
    float x = slots[i * 256 + t];
    float a = x, bq = x * x;
#pragma unroll
    for (int off = 32; off; off >>= 1) { a += __shfl_down(a, off); bq += __shfl_down(bq, off); }
    if ((t & 63) == 0) { red[t >> 6] = a; red[4 + (t >> 6)] = bq; }
  }
  __syncthreads();
  if (t < 256) {
    float x = slots[i * 256 + t];
    float S1 = red[0] + red[1] + red[2] + red[3];
    float S2 = red[4] + red[5] + red[6] + red[7];
    float m = S1 * (1.f / 256.f);
    float var = S2 * (1.f / 256.f) - m * m;
    float rstd = rsqrtf(var + LN_EPS);
    ln[t] = (x - m) * rstd * g_sl[t] + b_sl[t];
  }
  __syncthreads();
  int col = t & 255, ks = t >> 8;
  float acc = 0.f;
#pragma unroll 16
  for (int dd = 0; dd < 64; dd++) {
    int d = ks * 64 + dd;
    acc += ln[d] * Wq[d * 256 + col];
  }
  part[ks][col] = acc;
  __syncthreads();
  if (t < 256) qs[t] = part[0][t] + part[1][t] + part[2][t] + part[3][t];
  __syncthreads();
  int h = t >> 8, d2 = t & 255;
  float tt = 0.f;
#pragma unroll 8
  for (int dp = 0; dp < 64; dp++)
    tt += qs[h * 64 + dp] * (float)WkT16[(h * 64 + dp) * 256 + d2];
  tq[((i >> 3) * 32 + h * 8 + (i & 7)) * 256 + d2] = (f16)(tt * 0.125f);
}

// ---------------- fused attn: MFMA dots + shuffle softmax + VALU PV ----------
// grid (32 b, 32 nchunk of 128 n), block 256 (4 waves). 2 subtiles of 64 n.
__global__ __launch_bounds__(256, 3) void attn_fused_k(
    const f16* __restrict__ xln16, const f16* __restrict__ tq,
    f16* __restrict__ y_part, float* __restrict__ sums_part)
{
  __shared__ u16 xs[64 * 256];       // 32KB, swizzled: slot = d8 ^ (row&31)
  __shared__ float att_s[64][36];    // 9KB
  __shared__ float asum_s[4][32];
  int b = blockIdx.x, nc = blockIdx.y, t = threadIdx.x;
  int nb = nc * 128;
  int w = t >> 6, l = t & 63;
  int lc = l & 15, lg = l >> 4;
  // hoist t B-frags (16KB per b, L1/L2-resident)
  h16x8 tb0[8], tb1[8];
#pragma unroll
  for (int k0 = 0; k0 < 8; k0++) {
    tb0[k0] = *(const h16x8*)(tq + (b * 32 + lc) * 256 + k0 * 32 + lg * 8);
    tb1[k0] = *(const h16x8*)(tq + (b * 32 + lc + 16) * 256 + k0 * 32 + lg * 8);
  }
  int d8 = t & 31, hg = t >> 5;
  float yacc[32];
#pragma unroll
  for (int i = 0; i < 32; i++) yacc[i] = 0.f;
  float as0 = 0.f, as1 = 0.f;

  for (int sub = 0; sub < 2; sub++) {
    __syncthreads();   // prev PV done with xs/att_s
    {
      int nl = t >> 2, q = t & 3;
      const h16x8* gsrc = (const h16x8*)(xln16 +
          ((long)(b * 4096 + nb + sub * 64 + nl)) * 256 + q * 64);
#pragma unroll
      for (int j = 0; j < 8; j++) {
        int sd8 = q * 8 + j;
        *(h16x8*)((char*)xs + nl * 512 + ((sd8 ^ (nl & 31)) << 4)) = gsrc[j];
      }
    }
    __syncthreads();   // xs ready
    // dots: D[n][hs] = sum_d xln[n][d] * t[hs][d]
    f32x4 D0 = {0,0,0,0}, D1 = {0,0,0,0};
    int arow = w * 16 + lc;
#pragma unroll
    for (int k0 = 0; k0 < 8; k0++) {
      int ad8 = k0 * 4 + lg;
      h16x8 af = *(const h16x8*)((char*)xs + arow * 512 + ((ad8 ^ (arow & 31)) << 4));
      D0 = __builtin_amdgcn_mfma_f32_16x16x32_f16(af, tb0[k0], D0, 0, 0, 0);
      D1 = __builtin_amdgcn_mfma_f32_16x16x32_f16(af, tb1[k0], D1, 0, 0, 0);
    }
    // softmax over the 8 slots of each head: cols hs live in 8 adjacent lanes
#pragma unroll
    for (int r = 0; r < 4; r++) {
      float d0 = D0[r], d1 = D1[r];
      float m0 = d0, m1 = d1;
      m0 = fmaxf(m0, __shfl_xor(m0, 1)); m0 = fmaxf(m0, __shfl_xor(m0, 2)); m0 = fmaxf(m0, __shfl_xor(m0, 4));
      m1 = fmaxf(m1, __shfl_xor(m1, 1)); m1 = fmaxf(m1, __shfl_xor(m1, 2)); m1 = fmaxf(m1, __shfl_xor(m1, 4));
      float e0 = __expf(d0 - m0), e1 = __expf(d1 - m1);
      float s0 = e0, s1 = e1;
      s0 += __shfl_xor(s0, 1); s0 += __shfl_xor(s0, 2); s0 += __shfl_xor(s0, 4);
      s1 += __shfl_xor(s1, 1); s1 += __shfl_xor(s1, 2); s1 += __shfl_xor(s1, 4);
      float a0 = e0 / s0, a1 = e1 / s1;
      as0 += a0; as1 += a1;
      int n = w * 16 + lg * 4 + r;     // D row
      att_s[n][lc] = a0;
      att_s[n][lc + 16] = a1;
    }
    __syncthreads();   // att_s ready
    // PV: yacc[hs][d] += att[n][hs] * xln[n][d]
    for (int nl = 0; nl < 64; nl++) {
      h16x8 xv = *(const h16x8*)((char*)xs + nl * 512 + ((d8 ^ (nl & 31)) << 4));
      float4 av = *(const float4*)&att_s[nl][hg * 4];
      float a4[4] = {av.x, av.y, av.z, av.w};
#pragma unroll
      for (int i = 0; i < 4; i++)
#pragma unroll
        for (int j = 0; j < 8; j++)
          yacc[i * 8 + j] += a4[i] * (float)xv[j];
    }
  }
  // attn-sum partials
  as0 += __shfl_xor(as0, 16); as0 += __shfl_xor(as0, 32);
  as1 += __shfl_xor(as1, 16); as1 += __shfl_xor(as1, 32);
  if (l < 16) { asum_s[w][l] = as0; asum_s[w][l + 16] = as1; }
  __syncthreads();
  if (t < 32)
    sums_part[(nc * 32 + b) * 32 + t] =
        asum_s[0][t] + asum_s[1][t] + asum_s[2][t] + asum_s[3][t];
#pragma unroll
  for (int i = 0; i < 4; i++) {
    h16x8 ov;
#pragma unroll
    for (int j = 0; j < 8; j++) ov[j] = (f16)yacc[i * 8 + j];
    *(h16x8*)(y_part + ((long)((nc * 32 + b) * 32 + hg * 4 + i)) * 256 + d8 * 8) = ov;
  }
}

// ---------------- combine: y-reduce + Wv + Wc + GRU + LN + MLP (+ fused next-t) --
// grid 256 (one slot row per block), block 1024
__global__ __launch_bounds__(1024) void combine_k(
    const f16* __restrict__ y_part, const float* __restrict__ sums_part,
    float* __restrict__ slots, const float* __restrict__ Wv,
    const float* __restrict__ Wc, const float* __restrict__ wihT,
    const float* __restrict__ whhT, const float* __restrict__ bih,
    const float* __restrict__ bhh, const float* __restrict__ g_ml,
    const float* __restrict__ b_ml, const float* __restrict__ W1,
    const float* __restrict__ b1, const float* __restrict__ W2,
    const float* __restrict__ b2, const float* __restrict__ g_sl,
    const float* __restrict__ b_sl, const float* __restrict__ Wq,
    const f16* __restrict__ WkT16, f16* __restrict__ tq, int cq)
{
  __shared__ float ysn[4][256];
  __shared__ float uls[256], cls[256], hls[256], sns[256], lns[256];
  __shared__ float gia[3][256], gha[3][256];
  __shared__ float hid[512];
  __shared__ float part2[4][256][2];
  __shared__ float part5[2][512];
  __shared__ float red[8];
  int t = threadIdx.x;
  int i = blockIdx.x;
  int b = i >> 3, k = i & 7;
  {
    int j = t >> 8, d = t & 255;   // j = head
    float den = ATT_EPS, yv = 0.f;
#pragma unroll 8
    for (int ncq = 0; ncq < 32; ncq++) {
      int hsrow = (ncq * 32 + b) * 32 + j * 8 + k;
      den += sums_part[hsrow];
      yv += (float)y_part[(long)hsrow * 256 + d];
    }
    ysn[j][d] = yv / den;
    if (t < 256) hls[t] = slots[i * 256 + t];
  }
  __syncthreads();
  int col = t & 255, ks = t >> 8;
  // ---- Wv
  {
    int h = col >> 6;
    float acc = 0.f;
#pragma unroll 16
    for (int dd = 0; dd < 64; dd++) {
      int d = ks * 64 + dd;
      acc += ysn[h][d] * Wv[d * 256 + col];
    }
    part2[ks][col][0] = acc;
  }
  __syncthreads();
  if (t < 256)
    uls[t] = part2[0][t][0] + part2[1][t][0] + part2[2][t][0] + part2[3][t][0];
  __syncthreads();
  // ---- Wc
  {
    float acc = 0.f;
#pragma unroll 16
    for (int dd = 0; dd < 64; dd++) {
      int d = ks * 64 + dd;
      acc += uls[d] * Wc[d * 256 + col];
    }
    part2[ks][col][0] = acc;
  }
  __syncthreads();
  if (t < 256)
    cls[t] = part2[0][t][0] + part2[1][t][0] + part2[2][t][0] + part2[3][t][0];
  __syncthreads();
  // ---- GRU gates
  for (int g = 0; g < 3; g++) {
    float ai = 0.f, ah = 0.f;
#pragma unroll 8
    for (int dd = 0; dd < 64; dd++) {
      int d = ks * 64 + dd;
      float wi = wihT[d * 768 + g * 256 + col];
      float wh = whhT[d * 768 + g * 256 + col];
      ai += cls[d] * wi;
      ah += hls[d] * wh;
    }
    part2[ks][col][0] = ai;
    part2[ks][col][1] = ah;
    __syncthreads();
    if (t < 256) {
      gia[g][t] = part2[0][t][0] + part2[1][t][0] + part2[2][t][0] + part2[3][t][0] + bih[g * 256 + t];
    } else if (t < 512) {
      int c = t & 255;
      gha[g][c] = part2[0][c][1] + part2[1][c][1] + part2[2][c][1] + part2[3][c][1] + bhh[g * 256 + c];
    }
    __syncthreads();
  }
  // ---- gates + LN
  if (t < 256) {
    float r = 1.f / (1.f + __expf(-(gia[0][t] + gha[0][t])));
    float z = 1.f / (1.f + __expf(-(gia[1][t] + gha[1][t])));
    float nc2 = tanhf(gia[2][t] + r * gha[2][t]);
    float sn = (1.f - z) * nc2 + z * hls[t];
    sns[t] = sn;
    float a = sn, bq = sn * sn;
#pragma unroll
    for (int off = 32; off; off >>= 1) { a += __shfl_down(a, off); bq += __shfl_down(bq, off); }
    if ((t & 63) == 0) { red[t >> 6] = a; red[4 + (t >> 6)] = bq; }
  }
  __syncthreads();
  if (t < 256) {
    float S1 = red[0] + red[1] + red[2] + red[3];
    float S2 = red[4] + red[5] + red[6] + red[7];
    float mean = S1 * (1.f / 256.f);
    float var = S2 * (1.f / 256.f) - mean * mean;
    float rstd = rsqrtf(var + LN_EPS);
    lns[t] = (sns[t] - mean) * rstd * g_ml[t] + b_ml[t];
  }
  __syncthreads();
  // ---- W1
  {
    int c5 = t & 511, k5 = t >> 9;
    float acc = 0.f;
#pragma unroll 16
    for (int dd = 0; dd < 128; dd++) {
      int d = k5 * 128 + dd;
      acc += lns[d] * W1[d * 512 + c5];
    }
    part5[k5][c5] = acc;
  }
  __syncthreads();
  if (t < 512) hid[t] = fmaxf(part5[0][t] + part5[1][t] + b1[t], 0.f);
  __syncthreads();
  // ---- W2
  {
    float acc = 0.f;
#pragma unroll 16
    for (int dd = 0; dd < 128; dd++) {
      int d = ks * 128 + dd;
      acc += hid[d] * W2[d * 256 + col];
    }
    part2[ks][col][0] = acc;
  }
  __syncthreads();
  float outv = 0.f;
  if (t < 256) {
    outv = sns[t] + b2[t] +
        part2[0][t][0] + part2[1][t][0] + part2[2][t][0] + part2[3][t][0];
    slots[i * 256 + t] = outv;
  }
  // ---- fused t for next iteration
  if (cq) {
    if (t < 256) {
      float a = outv, bq = outv * outv;
#pragma unroll
      for (int off = 32; off; off >>= 1) { a += __shfl_down(a, off); bq += __shfl_down(bq, off); }
      if ((t & 63) == 0) { red[t >> 6] = a; red[4 + (t >> 6)] = bq; }
    }
    __syncthreads();
    if (t < 256) {
      float S1 = red[0] + red[1] + red[2] + red[3];
      float S2 = red[4] + red[5] + red[6] + red[7];
      float mean = S1 * (1.f / 256.f);
      float var = S2 * (1.f / 256.f) - mean * mean;
      float rstd = rsqrtf(var + LN_EPS);
      lns[t] = (outv - mean) * rstd * g_sl[t] + b_sl[t];
    }
    __syncthreads();
    float accq = 0.f;
#pragma unroll 16
    for (int dd = 0; dd < 64; dd++) {
      int d = ks * 64 + dd;
      accq += lns[d] * Wq[d * 256 + col];
    }
    part2[ks][col][0] = accq;
    __syncthreads();
    if (t < 256)
      uls[t] = part2[0][t][0] + part2[1][t][0] + part2[2][t][0] + part2[3][t][0];
    __syncthreads();
    int h2 = t >> 8, d2 = t & 255;
    float tt = 0.f;
#pragma unroll 8
    for (int dp = 0; dp < 64; dp++)
      tt += uls[h2 * 64 + dp] * (float)WkT16[(h2 * 64 + dp) * 256 + d2];
    tq[(b * 32 + h2 * 8 + k) * 256 + d2] = (f16)(tt * 0.125f);
  }
}

extern "C" void kernel_launch(void* const* d_in, const int* in_sizes, int n_in,
                              void* d_out, int out_size, void* d_ws, size_t ws_size,
                              hipStream_t stream)
{
  const float* inputs = (const float*)d_in[0];
  const float* noise  = (const float*)d_in[1];
  const float* mu     = (const float*)d_in[2];
  const float* lsig   = (const float*)d_in[3];
  const float* g_in   = (const float*)d_in[4];
  const float* b_in   = (const float*)d_in[5];
  const float* g_sl   = (const float*)d_in[6];
  const float* b_sl   = (const float*)d_in[7];
  const float* g_ml   = (const float*)d_in[8];
  const float* b_ml   = (const float*)d_in[9];
  const float* Wq     = (const float*)d_in[10];
  const float* Wk     = (const float*)d_in[11];
  const float* Wv     = (const float*)d_in[12];
  const float* Wc     = (const float*)d_in[13];
  const float* wih    = (const float*)d_in[14];
  const float* whh    = (const float*)d_in[15];
  const float* bih    = (const float*)d_in[16];
  const float* bhh    = (const float*)d_in[17];
  const float* W1     = (const float*)d_in[18];
  const float* b1     = (const float*)d_in[19];
  const float* W2     = (const float*)d_in[20];
  const float* b2     = (const float*)d_in[21];

  char* ws = (char*)d_ws;
  f16*   xln16  = (f16*)(ws);                      //  67,108,864
  f16*   y_part = (f16*)(ws + 67108864);           //  16,777,216
  f16*   tq     = (f16*)(ws + 83886080);           //     524,288
  float* slots  = (float*)(ws + 84410368);         //     262,144
  float* sumsp  = (float*)(ws + 84672512);         //     131,072
  f16*   WkT16  = (f16*)(ws + 84803584);           //     131,072
  float* wihT   = (float*)(ws + 84934656);         //     786,432
  float* whhT   = (float*)(ws + 85721088);         //     786,432  -> end 86,507,520

  init_slots_k<<<256, 256, 0, stream>>>(noise, mu, lsig, slots);
  prep_w_k<<<768, 256, 0, stream>>>(Wk, wih, whh, WkT16, wihT, whhT);
  ln_x_k<<<2048, 256, 0, stream>>>(inputs, g_in, b_in, xln16);
  slot_t_k<<<256, 1024, 0, stream>>>(slots, g_sl, b_sl, Wq, WkT16, tq);
  for (int it = 0; it < 3; ++it) {
    attn_fused_k<<<dim3(32, 32), 256, 0, stream>>>(xln16, tq, y_part, sumsp);
    combine_k<<<256, 1024, 0, stream>>>(y_part, sumsp, slots, Wv, Wc, wihT, whhT,
                                        bih, bhh, g_ml, b_ml, W1, b1, W2, b2,
                                        g_sl, b_sl, Wq, WkT16, tq, (it < 2) ? 1 : 0);
  }
  hipMemcpyAsync(d_out, slots, 65536 * sizeof(float), hipMemcpyDeviceToDevice, stream);
}

// Round 7
// 329.507 us; speedup vs baseline: 5.6944x; 1.2028x over previous
//
#include <hip/hip_runtime.h>
#include <hip/hip_bf16.h>
#include <stdint.h>

typedef unsigned short u16;
typedef _Float16 f16;
typedef __attribute__((ext_vector_type(4))) float f32x4;
typedef __attribute__((ext_vector_type(8))) _Float16 h16x8;
typedef __attribute__((ext_vector_type(4))) _Float16 h16x4;

#define LN_EPS 1e-5f
#define ATT_EPS 1e-8f

// ---------------- init slots: mu + exp(logsigma)*noise ----------------
__global__ __launch_bounds__(256) void init_slots_k(
    const float* __restrict__ noise, const float* __restrict__ mu,
    const float* __restrict__ lsig, float* __restrict__ slots)
{
  int i = blockIdx.x * 256 + threadIdx.x;   // 65536 total
  int d = i & 255;
  slots[i] = mu[d] + __expf(lsig[d]) * noise[i];
}

// ---------------- prep weights: WkT f16, wihT/whhT f32 ----------------
__global__ __launch_bounds__(256) void prep_w_k(
    const float* __restrict__ Wk, const float* __restrict__ wih,
    const float* __restrict__ whh,
    f16* __restrict__ WkT16, float* __restrict__ wihT, float* __restrict__ whhT)
{
  int i = blockIdx.x * 256 + threadIdx.x;   // grid 768 -> 196608
  if (i < 65536) {                           // WkT[c][kd] = Wk[kd][c]
    int c = i >> 8, kd = i & 255;
    WkT16[i] = (f16)Wk[kd * 256 + c];
  }
  int d = i / 768, j = i - d * 768;
  wihT[i] = wih[j * 256 + d];
  whhT[i] = whh[j * 256 + d];
}

// ---------------- pure LN pass: xln16 = LN(inputs) as f16 ----------------
// grid 2048, block 256 (4 waves): one wave per row, 16 rows/wave
__global__ __launch_bounds__(256) void ln_x_k(
    const float* __restrict__ inputs, const float* __restrict__ g_in,
    const float* __restrict__ b_in, f16* __restrict__ xln16)
{
  int t = threadIdx.x, w = t >> 6, l = t & 63;
  float4 gv = *(const float4*)(g_in + l * 4);
  float4 bv = *(const float4*)(b_in + l * 4);
  long row0 = (long)blockIdx.x * 64 + w * 16;
#pragma unroll 2
  for (int i = 0; i < 16; i++) {
    long r = row0 + i;
    float4 x = *(const float4*)(inputs + r * 256 + l * 4);
    float s1 = x.x + x.y + x.z + x.w;
    float s2 = x.x * x.x + x.y * x.y + x.z * x.z + x.w * x.w;
#pragma unroll
    for (int off = 1; off < 64; off <<= 1) {
      s1 += __shfl_xor(s1, off);
      s2 += __shfl_xor(s2, off);
    }
    float m = s1 * (1.f / 256.f);
    float var = s2 * (1.f / 256.f) - m * m;
    float rs = rsqrtf(var + LN_EPS);
    h16x4 o;
    o[0] = (f16)((x.x - m) * rs * gv.x + bv.x);
    o[1] = (f16)((x.y - m) * rs * gv.y + bv.y);
    o[2] = (f16)((x.z - m) * rs * gv.z + bv.z);
    o[3] = (f16)((x.w - m) * rs * gv.w + bv.w);
    *(h16x4*)(xln16 + r * 256 + l * 4) = o;
  }
}

// ---------------- t = (LN(slots)@Wq) projected through Wk heads, x SCALE ----
// grid 256 (one slot row per block), block 1024
__global__ __launch_bounds__(1024) void slot_t_k(
    const float* __restrict__ slots, const float* __restrict__ g_sl,
    const float* __restrict__ b_sl, const float* __restrict__ Wq,
    const f16* __restrict__ WkT16, f16* __restrict__ tq)
{
  __shared__ float ln[256];
  __shared__ float qs[256];
  __shared__ float part[4][256];
  __shared__ float red[8];
  int t = threadIdx.x;
  int i = blockIdx.x;
  if (t < 256) {
    float x = slots[i * 256 + t];
    float a = x, bq = x * x;
#pragma unroll
    for (int off = 32; off; off >>= 1) { a += __shfl_down(a, off); bq += __shfl_down(bq, off); }
    if ((t & 63) == 0) { red[t >> 6] = a; red[4 + (t >> 6)] = bq; }
  }
  __syncthreads();
  if (t < 256) {
    float x = slots[i * 256 + t];
    float S1 = red[0] + red[1] + red[2] + red[3];
    float S2 = red[4] + red[5] + red[6] + red[7];
    float m = S1 * (1.f / 256.f);
    float var = S2 * (1.f / 256.f) - m * m;
    float rstd = rsqrtf(var + LN_EPS);
    ln[t] = (x - m) * rstd * g_sl[t] + b_sl[t];
  }
  __syncthreads();
  int col = t & 255, ks = t >> 8;
  float acc = 0.f;
#pragma unroll 16
  for (int dd = 0; dd < 64; dd++) {
    int d = ks * 64 + dd;
    acc += ln[d] * Wq[d * 256 + col];
  }
  part[ks][col] = acc;
  __syncthreads();
  if (t < 256) qs[t] = part[0][t] + part[1][t] + part[2][t] + part[3][t];
  __syncthreads();
  int h = t >> 8, d2 = t & 255;
  float tt = 0.f;
#pragma unroll 8
  for (int dp = 0; dp < 64; dp++)
    tt += qs[h * 64 + dp] * (float)WkT16[(h * 64 + dp) * 256 + d2];
  tq[((i >> 3) * 32 + h * 8 + (i & 7)) * 256 + d2] = (f16)(tt * 0.125f);
}

// ---------------- fused attn: MFMA dots + shuffle softmax + MFMA PV ----------
// grid (32 b, 32 nchunk of 128 n), block 256 (4 waves). 2 subtiles of 64 n.
// LDS: xsT = transposed x_ln [256 d][64 n] (16B slot-swizzled), attT [32 hs][64 n].
__global__ __launch_bounds__(256, 3) void attn_fused_k(
    const f16* __restrict__ xln16, const f16* __restrict__ tq,
    f16* __restrict__ y_part, float* __restrict__ sums_part)
{
  __shared__ u16 xsT[256 * 64];      // 32KB: addr = d*128 + ((n8 ^ (d&7))<<4)
  __shared__ u16 attT[32 * 64];      // 4KB:  addr = hs*128 + ((n8 ^ (hs&7))<<4)
  __shared__ float asum_s[4][32];
  int b = blockIdx.x, nc = blockIdx.y, t = threadIdx.x;
  int nb = nc * 128;
  int w = t >> 6, l = t & 63;
  int lc = l & 15, lg = l >> 4;
  // hoist t B-frags (dots): tq rows hs, d-contig
  h16x8 tb0[8], tb1[8];
#pragma unroll
  for (int k0 = 0; k0 < 8; k0++) {
    tb0[k0] = *(const h16x8*)(tq + (b * 32 + lc) * 256 + k0 * 32 + lg * 8);
    tb1[k0] = *(const h16x8*)(tq + (b * 32 + lc + 16) * 256 + k0 * 32 + lg * 8);
  }
  f32x4 acc0[4], acc1[4];
#pragma unroll
  for (int dt = 0; dt < 4; dt++) { acc0[dt] = (f32x4){0,0,0,0}; acc1[dt] = (f32x4){0,0,0,0}; }
  float as0 = 0.f, as1 = 0.f;

  for (int sub = 0; sub < 2; sub++) {
    __syncthreads();   // previous PV done with xsT/attT
    // ---- transpose-stage xsT: thread reads 8 rows x 8 d, transposes in-reg
    {
      int nl8 = t >> 5, dchunk = t & 31;
      const f16* gp = xln16 + ((long)(b * 4096 + nb + sub * 64 + nl8 * 8)) * 256 + dchunk * 8;
      h16x8 v0 = *(const h16x8*)(gp);
      h16x8 v1 = *(const h16x8*)(gp + 256);
      h16x8 v2 = *(const h16x8*)(gp + 512);
      h16x8 v3 = *(const h16x8*)(gp + 768);
      h16x8 v4 = *(const h16x8*)(gp + 1024);
      h16x8 v5 = *(const h16x8*)(gp + 1280);
      h16x8 v6 = *(const h16x8*)(gp + 1536);
      h16x8 v7 = *(const h16x8*)(gp + 1792);
#pragma unroll
      for (int j = 0; j < 8; j++) {
        h16x8 o;
        o[0] = v0[j]; o[1] = v1[j]; o[2] = v2[j]; o[3] = v3[j];
        o[4] = v4[j]; o[5] = v5[j]; o[6] = v6[j]; o[7] = v7[j];
        int d = dchunk * 8 + j;
        *(h16x8*)((char*)xsT + d * 128 + ((nl8 ^ j) << 4)) = o;
      }
    }
    // ---- dots: A-frags straight from global (L1/L2-hot), B = hoisted t
    f32x4 D0 = {0,0,0,0}, D1 = {0,0,0,0};
    {
      const f16* ga = xln16 + ((long)(b * 4096 + nb + sub * 64 + w * 16 + lc)) * 256 + lg * 8;
#pragma unroll
      for (int k0 = 0; k0 < 8; k0++) {
        h16x8 af = *(const h16x8*)(ga + k0 * 32);
        D0 = __builtin_amdgcn_mfma_f32_16x16x32_f16(af, tb0[k0], D0, 0, 0, 0);
        D1 = __builtin_amdgcn_mfma_f32_16x16x32_f16(af, tb1[k0], D1, 0, 0, 0);
      }
    }
    // ---- softmax over 8 slots/head (hs in adjacent lanes) + transposed att store
    h16x4 pk0, pk1;
#pragma unroll
    for (int r = 0; r < 4; r++) {
      float d0 = D0[r], d1 = D1[r];
      float m0 = d0, m1 = d1;
      m0 = fmaxf(m0, __shfl_xor(m0, 1)); m0 = fmaxf(m0, __shfl_xor(m0, 2)); m0 = fmaxf(m0, __shfl_xor(m0, 4));
      m1 = fmaxf(m1, __shfl_xor(m1, 1)); m1 = fmaxf(m1, __shfl_xor(m1, 2)); m1 = fmaxf(m1, __shfl_xor(m1, 4));
      float e0 = __expf(d0 - m0), e1 = __expf(d1 - m1);
      float s0 = e0, s1 = e1;
      s0 += __shfl_xor(s0, 1); s0 += __shfl_xor(s0, 2); s0 += __shfl_xor(s0, 4);
      s1 += __shfl_xor(s1, 1); s1 += __shfl_xor(s1, 2); s1 += __shfl_xor(s1, 4);
      f16 a0h = (f16)(e0 / s0), a1h = (f16)(e1 / s1);
      as0 += (float)a0h; as1 += (float)a1h;
      pk0[r] = a0h; pk1[r] = a1h;
    }
    {
      int slot = w * 2 + (lg >> 1);
      int boff = (lg & 1) * 8;
      *(h16x4*)((char*)attT + lc * 128 + ((slot ^ (lc & 7)) << 4) + boff) = pk0;
      *(h16x4*)((char*)attT + (lc + 16) * 128 + ((slot ^ (lc & 7)) << 4) + boff) = pk1;
    }
    __syncthreads();   // xsT + attT ready
    // ---- PV via MFMA: y[hs][d] += att^T[hs][n] * xln[n][d]
    h16x8 A00, A01, A10, A11;
    {
      int hs0 = lc, hs1 = 16 + lc, sw = lc & 7;
      A00 = *(const h16x8*)((char*)attT + hs0 * 128 + ((lg ^ sw) << 4));
      A01 = *(const h16x8*)((char*)attT + hs0 * 128 + (((4 + lg) ^ sw) << 4));
      A10 = *(const h16x8*)((char*)attT + hs1 * 128 + ((lg ^ sw) << 4));
      A11 = *(const h16x8*)((char*)attT + hs1 * 128 + (((4 + lg) ^ sw) << 4));
    }
#pragma unroll
    for (int dt = 0; dt < 4; dt++) {
      int d = w * 64 + dt * 16 + lc;
      h16x8 B0 = *(const h16x8*)((char*)xsT + d * 128 + ((lg ^ (d & 7)) << 4));
      h16x8 B1 = *(const h16x8*)((char*)xsT + d * 128 + (((4 + lg) ^ (d & 7)) << 4));
      acc0[dt] = __builtin_amdgcn_mfma_f32_16x16x32_f16(A00, B0, acc0[dt], 0, 0, 0);
      acc0[dt] = __builtin_amdgcn_mfma_f32_16x16x32_f16(A01, B1, acc0[dt], 0, 0, 0);
      acc1[dt] = __builtin_amdgcn_mfma_f32_16x16x32_f16(A10, B0, acc1[dt], 0, 0, 0);
      acc1[dt] = __builtin_amdgcn_mfma_f32_16x16x32_f16(A11, B1, acc1[dt], 0, 0, 0);
    }
  }
  // ---- attn-sum partials
  as0 += __shfl_xor(as0, 16); as0 += __shfl_xor(as0, 32);
  as1 += __shfl_xor(as1, 16); as1 += __shfl_xor(as1, 32);
  if (l < 16) { asum_s[w][l] = as0; asum_s[w][l + 16] = as1; }
  __syncthreads();
  if (t < 32)
    sums_part[(nc * 32 + b) * 32 + t] =
        asum_s[0][t] + asum_s[1][t] + asum_s[2][t] + asum_s[3][t];
  // ---- y_part writes (D-frag layout: col=lane&15 -> d, row=(lane>>4)*4+reg -> hs)
  long ybase = ((long)(nc * 32 + b) * 32) * 256;
#pragma unroll
  for (int reg = 0; reg < 4; reg++) {
    int hsA = lg * 4 + reg;
#pragma unroll
    for (int dt = 0; dt < 4; dt++) {
      int d = w * 64 + dt * 16 + lc;
      y_part[ybase + hsA * 256 + d] = (f16)acc0[dt][reg];
      y_part[ybase + (16 + hsA) * 256 + d] = (f16)acc1[dt][reg];
    }
  }
}

// ---------------- combine: y-reduce + Wv + Wc + GRU + LN + MLP (+ fused next-t) --
// grid 256 (one slot row per block), block 1024
__global__ __launch_bounds__(1024) void combine_k(
    const f16* __restrict__ y_part, const float* __restrict__ sums_part,
    float* __restrict__ slots, const float* __restrict__ Wv,
    const float* __restrict__ Wc, const float* __restrict__ wihT,
    const float* __restrict__ whhT, const float* __restrict__ bih,
    const float* __restrict__ bhh, const float* __restrict__ g_ml,
    const float* __restrict__ b_ml, const float* __restrict__ W1,
    const float* __restrict__ b1, const float* __restrict__ W2,
    const float* __restrict__ b2, const float* __restrict__ g_sl,
    const float* __restrict__ b_sl, const float* __restrict__ Wq,
    const f16* __restrict__ WkT16, f16* __restrict__ tq, int cq)
{
  __shared__ float ysn[4][256];
  __shared__ float uls[256], cls[256], hls[256], sns[256], lns[256];
  __shared__ float gia[3][256], gha[3][256];
  __shared__ float hid[512];
  __shared__ float part2[4][256][2];
  __shared__ float part5[2][512];
  __shared__ float red[8];
  int t = threadIdx.x;
  int i = blockIdx.x;
  int b = i >> 3, k = i & 7;
  {
    int j = t >> 8, d = t & 255;   // j = head
    float den = ATT_EPS, yv = 0.f;
#pragma unroll 8
    for (int ncq = 0; ncq < 32; ncq++) {
      int hsrow = (ncq * 32 + b) * 32 + j * 8 + k;
      den += sums_part[hsrow];
      yv += (float)y_part[(long)hsrow * 256 + d];
    }
    ysn[j][d] = yv / den;
    if (t < 256) hls[t] = slots[i * 256 + t];
  }
  __syncthreads();
  int col = t & 255, ks = t >> 8;
  // ---- Wv
  {
    int h = col >> 6;
    float acc = 0.f;
#pragma unroll 16
    for (int dd = 0; dd < 64; dd++) {
      int d = ks * 64 + dd;
      acc += ysn[h][d] * Wv[d * 256 + col];
    }
    part2[ks][col][0] = acc;
  }
  __syncthreads();
  if (t < 256)
    uls[t] = part2[0][t][0] + part2[1][t][0] + part2[2][t][0] + part2[3][t][0];
  __syncthreads();
  // ---- Wc
  {
    float acc = 0.f;
#pragma unroll 16
    for (int dd = 0; dd < 64; dd++) {
      int d = ks * 64 + dd;
      acc += uls[d] * Wc[d * 256 + col];
    }
    part2[ks][col][0] = acc;
  }
  __syncthreads();
  if (t < 256)
    cls[t] = part2[0][t][0] + part2[1][t][0] + part2[2][t][0] + part2[3][t][0];
  __syncthreads();
  // ---- GRU gates
  for (int g = 0; g < 3; g++) {
    float ai = 0.f, ah = 0.f;
#pragma unroll 8
    for (int dd = 0; dd < 64; dd++) {
      int d = ks * 64 + dd;
      float wi = wihT[d * 768 + g * 256 + col];
      float wh = whhT[d * 768 + g * 256 + col];
      ai += cls[d] * wi;
      ah += hls[d] * wh;
    }
    part2[ks][col][0] = ai;
    part2[ks][col][1] = ah;
    __syncthreads();
    if (t < 256) {
      gia[g][t] = part2[0][t][0] + part2[1][t][0] + part2[2][t][0] + part2[3][t][0] + bih[g * 256 + t];
    } else if (t < 512) {
      int c = t & 255;
      gha[g][c] = part2[0][c][1] + part2[1][c][1] + part2[2][c][1] + part2[3][c][1] + bhh[g * 256 + c];
    }
    __syncthreads();
  }
  // ---- gates + LN
  if (t < 256) {
    float r = 1.f / (1.f + __expf(-(gia[0][t] + gha[0][t])));
    float z = 1.f / (1.f + __expf(-(gia[1][t] + gha[1][t])));
    float nc2 = tanhf(gia[2][t] + r * gha[2][t]);
    float sn = (1.f - z) * nc2 + z * hls[t];
    sns[t] = sn;
    float a = sn, bq = sn * sn;
#pragma unroll
    for (int off = 32; off; off >>= 1) { a += __shfl_down(a, off); bq += __shfl_down(bq, off); }
    if ((t & 63) == 0) { red[t >> 6] = a; red[4 + (t >> 6)] = bq; }
  }
  __syncthreads();
  if (t < 256) {
    float S1 = red[0] + red[1] + red[2] + red[3];
    float S2 = red[4] + red[5] + red[6] + red[7];
    float mean = S1 * (1.f / 256.f);
    float var = S2 * (1.f / 256.f) - mean * mean;
    float rstd = rsqrtf(var + LN_EPS);
    lns[t] = (sns[t] - mean) * rstd * g_ml[t] + b_ml[t];
  }
  __syncthreads();
  // ---- W1
  {
    int c5 = t & 511, k5 = t >> 9;
    float acc = 0.f;
#pragma unroll 16
    for (int dd = 0; dd < 128; dd++) {
      int d = k5 * 128 + dd;
      acc += lns[d] * W1[d * 512 + c5];
    }
    part5[k5][c5] = acc;
  }
  __syncthreads();
  if (t < 512) hid[t] = fmaxf(part5[0][t] + part5[1][t] + b1[t], 0.f);
  __syncthreads();
  // ---- W2
  {
    float acc = 0.f;
#pragma unroll 16
    for (int dd = 0; dd < 128; dd++) {
      int d = ks * 128 + dd;
      acc += hid[d] * W2[d * 256 + col];
    }
    part2[ks][col][0] = acc;
  }
  __syncthreads();
  float outv = 0.f;
  if (t < 256) {
    outv = sns[t] + b2[t] +
        part2[0][t][0] + part2[1][t][0] + part2[2][t][0] + part2[3][t][0];
    slots[i * 256 + t] = outv;
  }
  // ---- fused t for next iteration
  if (cq) {
    if (t < 256) {
      float a = outv, bq = outv * outv;
#pragma unroll
      for (int off = 32; off; off >>= 1) { a += __shfl_down(a, off); bq += __shfl_down(bq, off); }
      if ((t & 63) == 0) { red[t >> 6] = a; red[4 + (t >> 6)] = bq; }
    }
    __syncthreads();
    if (t < 256) {
      float S1 = red[0] + red[1] + red[2] + red[3];
      float S2 = red[4] + red[5] + red[6] + red[7];
      float mean = S1 * (1.f / 256.f);
      float var = S2 * (1.f / 256.f) - mean * mean;
      float rstd = rsqrtf(var + LN_EPS);
      lns[t] = (outv - mean) * rstd * g_sl[t] + b_sl[t];
    }
    __syncthreads();
    float accq = 0.f;
#pragma unroll 16
    for (int dd = 0; dd < 64; dd++) {
      int d = ks * 64 + dd;
      accq += lns[d] * Wq[d * 256 + col];
    }
    part2[ks][col][0] = accq;
    __syncthreads();
    if (t < 256)
      uls[t] = part2[0][t][0] + part2[1][t][0] + part2[2][t][0] + part2[3][t][0];
    __syncthreads();
    int h2 = t >> 8, d2 = t & 255;
    float tt = 0.f;
#pragma unroll 8
    for (int dp = 0; dp < 64; dp++)
      tt += uls[h2 * 64 + dp] * (float)WkT16[(h2 * 64 + dp) * 256 + d2];
    tq[(b * 32 + h2 * 8 + k) * 256 + d2] = (f16)(tt * 0.125f);
  }
}

extern "C" void kernel_launch(void* const* d_in, const int* in_sizes, int n_in,
                              void* d_out, int out_size, void* d_ws, size_t ws_size,
                              hipStream_t stream)
{
  const float* inputs = (const float*)d_in[0];
  const float* noise  = (const float*)d_in[1];
  const float* mu     = (const float*)d_in[2];
  const float* lsig   = (const float*)d_in[3];
  const float* g_in   = (const float*)d_in[4];
  const float* b_in   = (const float*)d_in[5];
  const float* g_sl   = (const float*)d_in[6];
  const float* b_sl   = (const float*)d_in[7];
  const float* g_ml   = (const float*)d_in[8];
  const float* b_ml   = (const float*)d_in[9];
  const float* Wq     = (const float*)d_in[10];
  const float* Wk     = (const float*)d_in[11];
  const float* Wv     = (const float*)d_in[12];
  const float* Wc     = (const float*)d_in[13];
  const float* wih    = (const float*)d_in[14];
  const float* whh    = (const float*)d_in[15];
  const float* bih    = (const float*)d_in[16];
  const float* bhh    = (const float*)d_in[17];
  const float* W1     = (const float*)d_in[18];
  const float* b1     = (const float*)d_in[19];
  const float* W2     = (const float*)d_in[20];
  const float* b2     = (const float*)d_in[21];

  char* ws = (char*)d_ws;
  f16*   xln16  = (f16*)(ws);                      //  67,108,864
  f16*   y_part = (f16*)(ws + 67108864);           //  16,777,216
  f16*   tq     = (f16*)(ws + 83886080);           //     524,288
  float* slots  = (float*)(ws + 84410368);         //     262,144
  float* sumsp  = (float*)(ws + 84672512);         //     131,072
  f16*   WkT16  = (f16*)(ws + 84803584);           //     131,072
  float* wihT   = (float*)(ws + 84934656);         //     786,432
  float* whhT   = (float*)(ws + 85721088);         //     786,432  -> end 86,507,520

  init_slots_k<<<256, 256, 0, stream>>>(noise, mu, lsig, slots);
  prep_w_k<<<768, 256, 0, stream>>>(Wk, wih, whh, WkT16, wihT, whhT);
  ln_x_k<<<2048, 256, 0, stream>>>(inputs, g_in, b_in, xln16);
  slot_t_k<<<256, 1024, 0, stream>>>(slots, g_sl, b_sl, Wq, WkT16, tq);
  for (int it = 0; it < 3; ++it) {
    attn_fused_k<<<dim3(32, 32), 256, 0, stream>>>(xln16, tq, y_part, sumsp);
    combine_k<<<256, 1024, 0, stream>>>(y_part, sumsp, slots, Wv, Wc, wihT, whhT,
                                        bih, bhh, g_ml, b_ml, W1, b1, W2, b2,
                                        g_sl, b_sl, Wq, WkT16, tq, (it < 2) ? 1 : 0);
  }
  hipMemcpyAsync(d_out, slots, 65536 * sizeof(float), hipMemcpyDeviceToDevice, stream);
}